// Round 9
// baseline (829.259 us; speedup 1.0000x reference)
//
#include <hip/hip_runtime.h>
#include <hip/hip_bf16.h>

#define NN 50000
#define EE 100000
#define BB 2000
#define DIM 64
#define NF 14
#define EF 4
#define HID 128
#define EPAD 100096   // 391*256 = 782*128
#define EPAD2 100352  // he16 padded allocation

typedef __attribute__((ext_vector_type(8))) _Float16 half8;   // 4 VGPRs
typedef __attribute__((ext_vector_type(4))) _Float16 half4;
typedef __attribute__((ext_vector_type(4))) float floatx4;    // MFMA C/D

__device__ __forceinline__ float rcp_fast(float x) { return __builtin_amdgcn_rcpf(x); }
__device__ __forceinline__ float sig_fast(float x) { return rcp_fast(1.f + __expf(-x)); }
__device__ __forceinline__ float tanh_fast(float x) {
    float e = __expf(2.f * x);
    return 1.f - 2.f * rcp_fast(e + 1.f);
}

// ---------------- fused preamble: w2rt + transposes + gru-prep + he16(+deg) + lin0 ----
__global__ void prep_fused_kernel(
    const float* __restrict__ x, const float* __restrict__ lin0_w,
    const float* __restrict__ lin0_b, float* __restrict__ hv,
    const float* __restrict__ ea, const float* __restrict__ w1,
    const float* __restrict__ b1, _Float16* __restrict__ he,
    const int* __restrict__ ei, float* __restrict__ deg,
    const float* __restrict__ w2, _Float16* __restrict__ W2rT,
    const float* __restrict__ lih, const float* __restrict__ lhh,
    const float* __restrict__ l1, float* __restrict__ lihT,
    float* __restrict__ lhhT, float* __restrict__ l1T,
    const float* __restrict__ root, const float* __restrict__ b2,
    const float* __restrict__ gwih, const float* __restrict__ gwhh,
    const float* __restrict__ gbih, const float* __restrict__ gbhh,
    _Float16* __restrict__ W1h, _Float16* __restrict__ W2h,
    float* __restrict__ fbias) {
    int t = blockIdx.x * 256 + threadIdx.x;

    // --- he16 (vectorized, 8 h/thread) + deg atomic; rows >= EE zero-padded ---
    {
        int el = t >> 4, hc = t & 15;
        if (el < EPAD2) {
            half8 o8 = {0, 0, 0, 0, 0, 0, 0, 0};
            if (el < EE) {
                const float4 a = *(const float4*)(ea + (size_t)el * 4);
                #pragma unroll
                for (int j = 0; j < 8; j++) {
                    int h = hc * 8 + j;
                    const float4 w = *(const float4*)(w1 + h * 4);
                    float acc = fmaxf(b1[h] + a.x * w.x + a.y * w.y + a.z * w.z + a.w * w.w, 0.f);
                    o8[j] = (_Float16)acc;
                }
                if (hc == 0) atomicAdd(&deg[ei[EE + el]], 1.0f);
            }
            *(half8*)(he + (size_t)el * 128 + hc * 8) = o8;
        }
    }
    // --- lin0 (vectorized, 8 d/thread): t < NN*8 ---
    if (t < NN * 8) {
        int n = t >> 3, dc = t & 7;
        float xv[NF];
        #pragma unroll
        for (int f = 0; f < NF; f++) xv[f] = x[(size_t)n * NF + f];
        float o[8];
        #pragma unroll
        for (int j = 0; j < 8; j++) {
            int d = dc * 8 + j;
            float acc = lin0_b[d];
            #pragma unroll
            for (int f = 0; f < NF; f++) acc += xv[f] * lin0_w[d * NF + f];
            o[j] = fmaxf(acc, 0.f);
        }
        *(float4*)(hv + (size_t)n * 64 + dc * 8)     = make_float4(o[0], o[1], o[2], o[3]);
        *(float4*)(hv + (size_t)n * 64 + dc * 8 + 4) = make_float4(o[4], o[5], o[6], o[7]);
    }
    // --- w2rt (vectorized, 8 k/thread): t < 64*1024 ---
    if (t < 64 * 1024) {
        int o = t >> 10, kc = t & 1023;
        int k0 = kc * 8, i = k0 >> 7, h0 = k0 & 127;
        const float* src = w2 + (size_t)(i * 64 + o) * 128 + h0;
        const float4 a = *(const float4*)src;
        const float4 b = *(const float4*)(src + 4);
        half8 r = {(_Float16)a.x, (_Float16)a.y, (_Float16)a.z, (_Float16)a.w,
                   (_Float16)b.x, (_Float16)b.y, (_Float16)b.z, (_Float16)b.w};
        *(half8*)(W2rT + (size_t)o * 8192 + k0) = r;
    }
    // --- set2set weight transposes ---
    if (t < 256 * 128) { int j = t / 128, k = t % 128; lihT[k * 256 + j] = lih[t]; }
    if (t < 256 * 64) { int j = t / 64, k = t % 64; lhhT[k * 256 + j] = lhh[t]; }
    if (t < 64 * 128) { int d = t / 128, k = t % 128; l1T[k * 64 + d] = l1[t]; }
    // --- gru weight prep ---
    if (t < 64 * 128) {
        int n = t >> 7, k = t & 127;
        W1h[t] = (_Float16)(k < 64 ? root[k * 64 + n] : b2[(size_t)(k - 64) * 64 + n]);
    }
    if (t < 256 * 128) {
        int n2 = t >> 7, k = t & 127;
        int g = n2 >> 6, j = n2 & 63;
        float v;
        if (g == 0)      v = (k < 64) ? gwih[j * 64 + k]         : gwhh[j * 64 + (k - 64)];
        else if (g == 1) v = (k < 64) ? gwih[(64 + j) * 64 + k]  : gwhh[(64 + j) * 64 + (k - 64)];
        else if (g == 2) v = (k < 64) ? gwih[(128 + j) * 64 + k] : 0.f;
        else             v = (k < 64) ? 0.f                      : gwhh[(128 + j) * 64 + (k - 64)];
        W2h[t] = (_Float16)v;
    }
    if (t < 256) {
        int g = t >> 6, j = t & 63;
        float v = (g == 0) ? gbih[j] + gbhh[j]
                : (g == 1) ? gbih[64 + j] + gbhh[64 + j]
                : (g == 2) ? gbih[128 + j] : gbhh[128 + j];
        fbias[t] = v;
    }
}

// ---------------- msg GEMM v1: the verified 134us kernel (setprio removed) -----------
__global__ __launch_bounds__(256, 2) void msg_gemm_kernel(
    const float* __restrict__ hv, const _Float16* __restrict__ he16,
    const _Float16* __restrict__ W2rT, const int* __restrict__ ei,
    float* __restrict__ agg, float* __restrict__ xsum) {
    __shared__ _Float16 sB[2][16 * 64 * 8];   // [frag(nt*4+ks)][lane][8]
    __shared__ _Float16 sXs[256 * 68];        // [edge][i], padded stride 68
    __shared__ int sDst[256];
    const int t = threadIdx.x;
    const int eb = blockIdx.x * 256;
    const int lane = t & 63;
    const int w = t >> 6;
    const int col = lane & 15;
    const int quad = lane >> 4;

    if (t < 256) {
        int e = eb + t;
        sDst[t] = (e < EE) ? ei[EE + e] : 0;
    }
    #pragma unroll 4
    for (int rep = 0; rep < 16; rep++) {
        int idx = rep * 256 + t;
        int el = idx >> 4, d4 = idx & 15;
        int e = eb + el;
        float4 v = {0.f, 0.f, 0.f, 0.f};
        if (e < EE) {
            int src = ei[e];
            v = *(const float4*)(hv + (size_t)src * 64 + d4 * 4);
        }
        half4 h4 = {(_Float16)v.x, (_Float16)v.y, (_Float16)v.z, (_Float16)v.w};
        *(half4*)&sXs[el * 68 + d4 * 4] = h4;
    }

    half8 heReg[4][4];
    #pragma unroll
    for (int mt = 0; mt < 4; mt++) {
        int row = eb + w * 64 + mt * 16 + col;
        #pragma unroll
        for (int p = 0; p < 4; p++)
            heReg[mt][p] = *(const half8*)(he16 + (size_t)row * 128 + p * 32 + quad * 8);
    }

    floatx4 Cacc[4][4];
    #pragma unroll
    for (int mt = 0; mt < 4; mt++)
        #pragma unroll
        for (int nt = 0; nt < 4; nt++)
            Cacc[mt][nt] = (floatx4){0.f, 0.f, 0.f, 0.f};

    const size_t gbase = (size_t)(w * 16 + col) * 8192 + quad * 8;
    half8 pre[4];
    {
        #pragma unroll
        for (int rep = 0; rep < 4; rep++)
            pre[rep] = *(const half8*)(W2rT + gbase + 0 * 128 + rep * 32);
        #pragma unroll
        for (int rep = 0; rep < 4; rep++)
            *(half8*)&sB[0][((w * 4 + rep) * 64 + lane) * 8] = pre[rep];
    }
    __syncthreads();

    #pragma unroll 1
    for (int i = 0; i < 64; i++) {
        int buf = i & 1;
        if (i < 63) {
            #pragma unroll
            for (int rep = 0; rep < 4; rep++)
                pre[rep] = *(const half8*)(W2rT + gbase + (size_t)(i + 1) * 128 + rep * 32);
        }
        _Float16 xsx[4];
        #pragma unroll
        for (int mt = 0; mt < 4; mt++)
            xsx[mt] = sXs[(w * 64 + mt * 16 + col) * 68 + i];
        #pragma unroll
        for (int ks = 0; ks < 4; ks++) {
            half8 bfr[4];
            #pragma unroll
            for (int nt = 0; nt < 4; nt++)
                bfr[nt] = *(const half8*)&sB[buf][((nt * 4 + ks) * 64 + lane) * 8];
            #pragma unroll
            for (int mt = 0; mt < 4; mt++) {
                half8 afr = heReg[mt][ks] * xsx[mt];
                #pragma unroll
                for (int nt = 0; nt < 4; nt++)
                    Cacc[mt][nt] = __builtin_amdgcn_mfma_f32_16x16x32_f16(afr, bfr[nt], Cacc[mt][nt], 0, 0, 0);
            }
        }
        if (i < 63) {
            #pragma unroll
            for (int rep = 0; rep < 4; rep++)
                *(half8*)&sB[buf ^ 1][((w * 4 + rep) * 64 + lane) * 8] = pre[rep];
        }
        __syncthreads();
    }

    #pragma unroll
    for (int mt = 0; mt < 4; mt++) {
        #pragma unroll
        for (int r = 0; r < 4; r++) {
            int el = w * 64 + mt * 16 + quad * 4 + r;
            if (eb + el < EE) {
                float* ap = agg + (size_t)sDst[el] * 64 + col;
                #pragma unroll
                for (int nt = 0; nt < 4; nt++)
                    atomicAdd(ap + nt * 16, Cacc[mt][nt][r]);
            }
        }
    }
    #pragma unroll 4
    for (int rep = 0; rep < 64; rep++) {
        int idx = rep * 256 + t;
        int el = idx >> 6, d = idx & 63;
        if (eb + el < EE)
            atomicAdd(&xsum[(size_t)sDst[el] * 64 + d], (float)sXs[el * 68 + d]);
    }
}

// ---------------- msg GEMM v2: 128-edge tile, 2-wave block, 3 blocks/CU --------------
// Per-wave structure IDENTICAL to v1 (M=64/wave, 16 B-frag reads : 64 MFMA per slice).
// Changes only the packing: grid 391 -> 782 blocks at 3/CU (LDS 50.7KB) -> loaded-CU
// work drops 512 -> 384 edges (x0.75), 2-wave barrier rendezvous, 3 staggered barrier
// domains per CU. Each wave stages 8 frags/slice (vs 4) since only 2 waves share sB.
__global__ __launch_bounds__(128, 2) void msg_gemm2_kernel(
    const float* __restrict__ hv, const _Float16* __restrict__ he16,
    const _Float16* __restrict__ W2rT, const int* __restrict__ ei,
    float* __restrict__ agg, float* __restrict__ xsum) {
    __shared__ _Float16 sB[2][16 * 64 * 8];   // 32KB
    __shared__ _Float16 sXs[128 * 68];        // 17.4KB
    __shared__ int sDst[128];
    const int t = threadIdx.x;
    const int eb = blockIdx.x * 128;
    const int lane = t & 63;
    const int w = t >> 6;        // 0..1
    const int col = lane & 15;
    const int quad = lane >> 4;

    if (t < 128) {
        int e = eb + t;
        sDst[t] = (e < EE) ? ei[EE + e] : 0;
    }
    #pragma unroll 4
    for (int rep = 0; rep < 16; rep++) {
        int idx = rep * 128 + t;
        int el = idx >> 4, d4 = idx & 15;
        int e = eb + el;
        float4 v = {0.f, 0.f, 0.f, 0.f};
        if (e < EE) {
            int src = ei[e];
            v = *(const float4*)(hv + (size_t)src * 64 + d4 * 4);
        }
        half4 h4 = {(_Float16)v.x, (_Float16)v.y, (_Float16)v.z, (_Float16)v.w};
        *(half4*)&sXs[el * 68 + d4 * 4] = h4;
    }

    half8 heReg[4][4];
    #pragma unroll
    for (int mt = 0; mt < 4; mt++) {
        int row = eb + w * 64 + mt * 16 + col;
        #pragma unroll
        for (int p = 0; p < 4; p++)
            heReg[mt][p] = *(const half8*)(he16 + (size_t)row * 128 + p * 32 + quad * 8);
    }

    floatx4 Cacc[4][4];
    #pragma unroll
    for (int mt = 0; mt < 4; mt++)
        #pragma unroll
        for (int nt = 0; nt < 4; nt++)
            Cacc[mt][nt] = (floatx4){0.f, 0.f, 0.f, 0.f};

    // staging: wave w owns frags f = w*8 .. w*8+7. Frag f at lane (col,quad):
    //   global: W2rT[((f>>2)*16+col)*8192 + i*128 + (f&3)*32 + quad*8]
    //   LDS:    sB[buf][(f*64+lane)*8]  (lane-sequential, conflict-free)
    size_t goff[8]; int woff[8];
    #pragma unroll
    for (int rep = 0; rep < 8; rep++) {
        int f = w * 8 + rep;
        goff[rep] = (size_t)((f >> 2) * 16 + col) * 8192 + (f & 3) * 32 + quad * 8;
        woff[rep] = (f * 64 + lane) * 8;
    }
    half8 pre[8];
    {
        #pragma unroll
        for (int rep = 0; rep < 8; rep++)
            pre[rep] = *(const half8*)(W2rT + goff[rep]);
        #pragma unroll
        for (int rep = 0; rep < 8; rep++)
            *(half8*)&sB[0][woff[rep]] = pre[rep];
    }
    __syncthreads();

    #pragma unroll 1
    for (int i = 0; i < 64; i++) {
        int buf = i & 1;
        if (i < 63) {
            #pragma unroll
            for (int rep = 0; rep < 8; rep++)
                pre[rep] = *(const half8*)(W2rT + goff[rep] + (size_t)(i + 1) * 128);
        }
        _Float16 xsx[4];
        #pragma unroll
        for (int mt = 0; mt < 4; mt++)
            xsx[mt] = sXs[(w * 64 + mt * 16 + col) * 68 + i];
        #pragma unroll
        for (int ks = 0; ks < 4; ks++) {
            half8 bfr[4];
            #pragma unroll
            for (int nt = 0; nt < 4; nt++)
                bfr[nt] = *(const half8*)&sB[buf][((nt * 4 + ks) * 64 + lane) * 8];
            #pragma unroll
            for (int mt = 0; mt < 4; mt++) {
                half8 afr = heReg[mt][ks] * xsx[mt];
                #pragma unroll
                for (int nt = 0; nt < 4; nt++)
                    Cacc[mt][nt] = __builtin_amdgcn_mfma_f32_16x16x32_f16(afr, bfr[nt], Cacc[mt][nt], 0, 0, 0);
            }
        }
        if (i < 63) {
            #pragma unroll
            for (int rep = 0; rep < 8; rep++)
                *(half8*)&sB[buf ^ 1][woff[rep]] = pre[rep];
        }
        __syncthreads();
    }

    #pragma unroll
    for (int mt = 0; mt < 4; mt++) {
        #pragma unroll
        for (int r = 0; r < 4; r++) {
            int el = w * 64 + mt * 16 + quad * 4 + r;
            if (eb + el < EE) {
                float* ap = agg + (size_t)sDst[el] * 64 + col;
                #pragma unroll
                for (int nt = 0; nt < 4; nt++)
                    atomicAdd(ap + nt * 16, Cacc[mt][nt][r]);
            }
        }
    }
    #pragma unroll 4
    for (int rep = 0; rep < 64; rep++) {
        int idx = rep * 128 + t;
        int el = idx >> 6, d = idx & 63;
        if (eb + el < EE)
            atomicAdd(&xsum[(size_t)sDst[el] * 64 + d], (float)sXs[el * 68 + d]);
    }
}

// ---------------- fused node update: NNConv epilogue + GRU (MFMA) ----------------
// hold values prefetched into registers before the stage-2 MFMA block (latency hidden
// under 64 MFMAs). Direct global store of h_new (rows block-exclusive).
__global__ __launch_bounds__(256, 3) void node_fused_kernel(
    const float* __restrict__ hv_in, float* __restrict__ agg,
    float* __restrict__ xsum, const float* __restrict__ deg,
    const _Float16* __restrict__ W1h, const _Float16* __restrict__ W2h,
    const float* __restrict__ fbias, const float* __restrict__ cb,
    float* __restrict__ hv_out) {
    __shared__ _Float16 sA1[64 * 136];  // [node][k]: k<64 hv, k>=64 xsum/deg
    __shared__ _Float16 sA2[64 * 136];  // [node][k]: k<64 m, k>=64 hv
    __shared__ float sAgg[64 * 68];     // agg/deg fp32
    const int t = threadIdx.x;
    const int nb = blockIdx.x * 64;
    const int n = t >> 2, part = t & 3;
    {
        int gn = nb + n;
        bool valid = gn < NN;
        float inv = 1.f;
        if (valid) inv = 1.f / fmaxf(deg[gn], 1.f);
        #pragma unroll
        for (int c4 = 0; c4 < 4; c4++) {
            int d0 = part * 16 + c4 * 4;
            float4 hvv = {0.f, 0.f, 0.f, 0.f}, agv = {0.f, 0.f, 0.f, 0.f}, xsv = {0.f, 0.f, 0.f, 0.f};
            if (valid) {
                hvv = *(const float4*)(hv_in + (size_t)gn * 64 + d0);
                agv = *(const float4*)(agg + (size_t)gn * 64 + d0);
                xsv = *(const float4*)(xsum + (size_t)gn * 64 + d0);
            }
            agv.x *= inv; agv.y *= inv; agv.z *= inv; agv.w *= inv;
            xsv.x *= inv; xsv.y *= inv; xsv.z *= inv; xsv.w *= inv;
            half4 hvh = {(_Float16)hvv.x, (_Float16)hvv.y, (_Float16)hvv.z, (_Float16)hvv.w};
            half4 xsh = {(_Float16)xsv.x, (_Float16)xsv.y, (_Float16)xsv.z, (_Float16)xsv.w};
            *(half4*)&sA1[n * 136 + d0] = hvh;
            *(half4*)&sA1[n * 136 + 64 + d0] = xsh;
            *(half4*)&sA2[n * 136 + 64 + d0] = hvh;
            *(float4*)&sAgg[n * 68 + d0] = agv;
        }
        // re-zero agg/xsum for the next msg_gemm launch
        if (valid) {
            float4 z = {0.f, 0.f, 0.f, 0.f};
            #pragma unroll
            for (int c4 = 0; c4 < 4; c4++) {
                int d0 = part * 16 + c4 * 4;
                *(float4*)(agg + (size_t)gn * 64 + d0) = z;
                *(float4*)(xsum + (size_t)gn * 64 + d0) = z;
            }
        }
    }
    __syncthreads();

    const int lane = t & 63, w = t >> 6;
    const int col = lane & 15, quad = lane >> 4;

    // ---- stage 1 ----
    floatx4 C1[4];
    #pragma unroll
    for (int nt = 0; nt < 4; nt++) {
        float b = cb[nt * 16 + col];
        C1[nt] = (floatx4){b, b, b, b};
    }
    #pragma unroll
    for (int ks = 0; ks < 4; ks++) {
        half8 a = *(const half8*)&sA1[(w * 16 + col) * 136 + ks * 32 + quad * 8];
        #pragma unroll
        for (int nt = 0; nt < 4; nt++) {
            half8 bfr = *(const half8*)(W1h + (size_t)(nt * 16 + col) * 128 + ks * 32 + quad * 8);
            C1[nt] = __builtin_amdgcn_mfma_f32_16x16x32_f16(a, bfr, C1[nt], 0, 0, 0);
        }
    }
    #pragma unroll
    for (int nt = 0; nt < 4; nt++) {
        #pragma unroll
        for (int r = 0; r < 4; r++) {
            int node = w * 16 + quad * 4 + r;
            int j = nt * 16 + col;
            float m = fmaxf(C1[nt][r] + sAgg[node * 68 + j], 0.f);
            sA2[node * 136 + j] = (_Float16)m;
        }
    }
    __syncthreads();

    // ---- hold prefetch (arrives during stage-2 MFMAs) ----
    float holdv[4][4];
    #pragma unroll
    for (int r = 0; r < 4; r++) {
        int node = w * 16 + quad * 4 + r;
        int gn2 = nb + node;
        #pragma unroll
        for (int jt = 0; jt < 4; jt++)
            holdv[r][jt] = (gn2 < NN) ? hv_in[(size_t)gn2 * 64 + jt * 16 + col] : 0.f;
    }

    // ---- stage 2 ----
    floatx4 C2[16];
    #pragma unroll
    for (int nt2 = 0; nt2 < 16; nt2++) {
        float b = fbias[nt2 * 16 + col];
        C2[nt2] = (floatx4){b, b, b, b};
    }
    #pragma unroll
    for (int ks = 0; ks < 4; ks++) {
        half8 a = *(const half8*)&sA2[(w * 16 + col) * 136 + ks * 32 + quad * 8];
        #pragma unroll
        for (int nt2 = 0; nt2 < 16; nt2++) {
            half8 bfr = *(const half8*)(W2h + (size_t)(nt2 * 16 + col) * 128 + ks * 32 + quad * 8);
            C2[nt2] = __builtin_amdgcn_mfma_f32_16x16x32_f16(a, bfr, C2[nt2], 0, 0, 0);
        }
    }
    // ---- GRU epilogue: registers only ----
    #pragma unroll
    for (int r = 0; r < 4; r++) {
        int node = w * 16 + quad * 4 + r;
        int gn2 = nb + node;
        if (gn2 < NN) {
            #pragma unroll
            for (int jt = 0; jt < 4; jt++) {
                int j = jt * 16 + col;
                float rr = sig_fast(C2[jt][r]);
                float zz = sig_fast(C2[4 + jt][r]);
                float ng = tanh_fast(C2[8 + jt][r] + rr * C2[12 + jt][r]);
                hv_out[(size_t)gn2 * 64 + j] = (1.f - zz) * ng + zz * holdv[r][jt];
            }
        }
    }
}

// ---------------- fused Set2Set (3 steps) + readout, one block per graph ----------------
__global__ __launch_bounds__(256) void set2set_kernel(
    const float* __restrict__ hv,
    const float* __restrict__ lihT, const float* __restrict__ lhhT,
    const float* __restrict__ l_bih, const float* __restrict__ l_bhh,
    const float* __restrict__ lin1T, const float* __restrict__ lin1_b,
    const float* __restrict__ lin2_w, const float* __restrict__ lin2_b,
    float* __restrict__ out) {
    __shared__ float outS[25 * 65];
    __shared__ float qs[128], qh[64], qc[64], gat[256], ew[32], aw[32], red[64];
    int g = blockIdx.x;
    int t = threadIdx.x;
    for (int p = t; p < 25 * 64; p += 256) {
        int j = p >> 6, i = p & 63;
        outS[j * 65 + i] = hv[(size_t)(g * 25 + j) * 64 + i];
    }
    if (t < 128) qs[t] = 0.f;
    if (t < 64) { qh[t] = 0.f; qc[t] = 0.f; }
    __syncthreads();
    for (int it = 0; it < 3; it++) {
        float acc = l_bih[t] + l_bhh[t];
        for (int k = 0; k < 128; k++) acc += qs[k] * lihT[k * 256 + t];
        for (int k = 0; k < 64; k++) acc += qh[k] * lhhT[k * 256 + t];
        gat[t] = acc;
        __syncthreads();
        if (t < 64) {
            float ig = sig_fast(gat[t]);
            float fg = sig_fast(gat[64 + t]);
            float gg = tanh_fast(gat[128 + t]);
            float og = sig_fast(gat[192 + t]);
            float c = fg * qc[t] + ig * gg;
            qc[t] = c;
            qh[t] = og * tanh_fast(c);
        }
        __syncthreads();
        if (t < 25) {
            float e = 0.f;
            for (int i = 0; i < 64; i++) e += outS[t * 65 + i] * qh[i];
            ew[t] = e;
        }
        __syncthreads();
        // wave-parallel softmax over the 25 graph nodes (lanes 0..31 of wave 0)
        if (t < 32) {
            float e = (t < 25) ? ew[t] : -1e30f;
            float mx = e;
            #pragma unroll
            for (int o = 16; o > 0; o >>= 1) mx = fmaxf(mx, __shfl_xor(mx, o, 32));
            float a = (t < 25) ? __expf(e - mx) : 0.f;
            float s = a;
            #pragma unroll
            for (int o = 16; o > 0; o >>= 1) s += __shfl_xor(s, o, 32);
            if (t < 25) aw[t] = a * rcp_fast(s);
        }
        __syncthreads();
        if (t < 64) {
            float r = 0.f;
            for (int j = 0; j < 25; j++) r += aw[j] * outS[j * 65 + t];
            qs[t] = qh[t];
            qs[64 + t] = r;
        }
        __syncthreads();
    }
    if (t < 64) {
        float y1 = lin1_b[t];
        for (int k = 0; k < 128; k++) y1 += qs[k] * lin1T[k * 64 + t];
        y1 = fmaxf(y1, 0.f);
        red[t] = y1 * lin2_w[t];
    }
    __syncthreads();
    if (t == 0) {
        float y = lin2_b[0];
        for (int i = 0; i < 64; i++) y += red[i];
        out[g] = y;
    }
}

extern "C" void kernel_launch(void* const* d_in, const int* in_sizes, int n_in,
                              void* d_out, int out_size, void* d_ws, size_t ws_size,
                              hipStream_t stream) {
    const float* x        = (const float*)d_in[0];
    const float* ea       = (const float*)d_in[1];
    const int*   ei       = (const int*)  d_in[2];
    const float* lin0_w   = (const float*)d_in[4];
    const float* lin0_b   = (const float*)d_in[5];
    const float* mlp_w1   = (const float*)d_in[6];
    const float* mlp_b1   = (const float*)d_in[7];
    const float* mlp_w2   = (const float*)d_in[8];
    const float* mlp_b2   = (const float*)d_in[9];
    const float* root     = (const float*)d_in[10];
    const float* conv_b   = (const float*)d_in[11];
    const float* gru_wih  = (const float*)d_in[12];
    const float* gru_whh  = (const float*)d_in[13];
    const float* gru_bih  = (const float*)d_in[14];
    const float* gru_bhh  = (const float*)d_in[15];
    const float* lstm_wih = (const float*)d_in[16];
    const float* lstm_whh = (const float*)d_in[17];
    const float* lstm_bih = (const float*)d_in[18];
    const float* lstm_bhh = (const float*)d_in[19];
    const float* lin1_w   = (const float*)d_in[20];
    const float* lin1_b   = (const float*)d_in[21];
    const float* lin2_w   = (const float*)d_in[22];
    const float* lin2_b   = (const float*)d_in[23];
    float* out = (float*)d_out;

    // ---- workspace carve ----
    char* base = (char*)d_ws;
    size_t off = 0;
    auto carve = [&](size_t bytes) -> void* {
        void* r = base + off;
        off = (off + bytes + 255) & ~(size_t)255;
        return r;
    };
    float* hv   = (float*)carve((size_t)NN * 64 * 4);
    float* agg  = (float*)carve((size_t)NN * 64 * 4);   // agg+xsum+deg adjacent: one memset
    float* xsum = (float*)carve((size_t)NN * 64 * 4);
    float* deg  = (float*)carve((size_t)NN * 4);
    float* lihT = (float*)carve(128 * 256 * 4);
    float* lhhT = (float*)carve(64 * 256 * 4);
    float* l1T  = (float*)carve(128 * 64 * 4);
    float* fbias = (float*)carve(256 * 4);
    _Float16* he16 = (_Float16*)carve((size_t)EPAD2 * 128 * 2);
    _Float16* W2rT = (_Float16*)carve((size_t)64 * 8192 * 2);
    _Float16* W1h  = (_Float16*)carve((size_t)64 * 128 * 2);
    _Float16* W2h  = (_Float16*)carve((size_t)256 * 128 * 2);

    // ---- preamble: one memset (agg+xsum+deg contiguous) + one fused prep kernel ----
    hipMemsetAsync(agg, 0, (size_t)NN * 64 * 4 * 2 + (size_t)NN * 4, stream);
    prep_fused_kernel<<<EPAD2 * 16 / 256, 256, 0, stream>>>(
        x, lin0_w, lin0_b, hv,
        ea, mlp_w1, mlp_b1, he16, ei, deg,
        mlp_w2, W2rT,
        lstm_wih, lstm_whh, lin1_w, lihT, lhhT, l1T,
        root, mlp_b2, gru_wih, gru_whh, gru_bih, gru_bhh,
        W1h, W2h, fbias);

    // ---- 3 message-passing + GRU iterations (node_fused re-zeros agg/xsum) ----
    // it=0 runs the v2 packing experiment (128-tile, 3 blocks/CU); it=1,2 run champion v1.
    for (int it = 0; it < 3; it++) {
        if (it == 0)
            msg_gemm2_kernel<<<EPAD / 128, 128, 0, stream>>>(hv, he16, W2rT, ei, agg, xsum);
        else
            msg_gemm_kernel<<<EPAD / 256, 256, 0, stream>>>(hv, he16, W2rT, ei, agg, xsum);
        node_fused_kernel<<<(NN + 63) / 64, 256, 0, stream>>>(hv, agg, xsum, deg,
                                                              W1h, W2h, fbias, conv_b, hv);
    }

    // ---- Set2Set + readout ----
    set2set_kernel<<<BB, 256, 0, stream>>>(hv, lihT, lhhT, lstm_bih, lstm_bhh,
                                           l1T, lin1_b, lin2_w, lin2_b, out);
}

// Round 10
// 740.204 us; speedup vs baseline: 1.1203x; 1.1203x over previous
//
#include <hip/hip_runtime.h>
#include <hip/hip_bf16.h>

#define NN 50000
#define EE 100000
#define BB 2000
#define DIM 64
#define NF 14
#define EF 4
#define HID 128
#define EPAD 100096   // 391*256 (msg tile grid)
#define EPAD2 100352  // he16 padded allocation

typedef __attribute__((ext_vector_type(8))) _Float16 half8;   // 4 VGPRs
typedef __attribute__((ext_vector_type(4))) _Float16 half4;
typedef __attribute__((ext_vector_type(4))) float floatx4;    // MFMA C/D

__device__ __forceinline__ float rcp_fast(float x) { return __builtin_amdgcn_rcpf(x); }
__device__ __forceinline__ float sig_fast(float x) { return rcp_fast(1.f + __expf(-x)); }
__device__ __forceinline__ float tanh_fast(float x) {
    float e = __expf(2.f * x);
    return 1.f - 2.f * rcp_fast(e + 1.f);
}

// ---------------- fused preamble: w2rt + transposes + gru-prep + he16(+deg) + lin0
//                  + agg/xsum zero-init (memset dispatch folded in) ----
__global__ void prep_fused_kernel(
    const float* __restrict__ x, const float* __restrict__ lin0_w,
    const float* __restrict__ lin0_b, float* __restrict__ hv,
    const float* __restrict__ ea, const float* __restrict__ w1,
    const float* __restrict__ b1, _Float16* __restrict__ he,
    const int* __restrict__ ei, float* __restrict__ deg,
    const float* __restrict__ w2, _Float16* __restrict__ W2rT,
    const float* __restrict__ lih, const float* __restrict__ lhh,
    const float* __restrict__ l1, float* __restrict__ lihT,
    float* __restrict__ lhhT, float* __restrict__ l1T,
    const float* __restrict__ root, const float* __restrict__ b2,
    const float* __restrict__ gwih, const float* __restrict__ gwhh,
    const float* __restrict__ gbih, const float* __restrict__ gbhh,
    _Float16* __restrict__ W1h, _Float16* __restrict__ W2h,
    float* __restrict__ fbias, float* __restrict__ aggxs) {
    int t = blockIdx.x * 256 + threadIdx.x;

    // --- agg+xsum zero-init (adjacent, 6.4M floats = 1.6M float4) ---
    if (t < NN * 64 * 2 / 4) {
        ((float4*)aggxs)[t] = make_float4(0.f, 0.f, 0.f, 0.f);
    }
    // --- he16 (vectorized, 8 h/thread) + deg atomic; rows >= EE zero-padded ---
    {
        int el = t >> 4, hc = t & 15;
        if (el < EPAD2) {
            half8 o8 = {0, 0, 0, 0, 0, 0, 0, 0};
            if (el < EE) {
                const float4 a = *(const float4*)(ea + (size_t)el * 4);
                #pragma unroll
                for (int j = 0; j < 8; j++) {
                    int h = hc * 8 + j;
                    const float4 w = *(const float4*)(w1 + h * 4);
                    float acc = fmaxf(b1[h] + a.x * w.x + a.y * w.y + a.z * w.z + a.w * w.w, 0.f);
                    o8[j] = (_Float16)acc;
                }
                if (hc == 0) atomicAdd(&deg[ei[EE + el]], 1.0f);
            }
            *(half8*)(he + (size_t)el * 128 + hc * 8) = o8;
        }
    }
    // --- lin0 (vectorized, 8 d/thread): t < NN*8 ---
    if (t < NN * 8) {
        int n = t >> 3, dc = t & 7;
        float xv[NF];
        #pragma unroll
        for (int f = 0; f < NF; f++) xv[f] = x[(size_t)n * NF + f];
        float o[8];
        #pragma unroll
        for (int j = 0; j < 8; j++) {
            int d = dc * 8 + j;
            float acc = lin0_b[d];
            #pragma unroll
            for (int f = 0; f < NF; f++) acc += xv[f] * lin0_w[d * NF + f];
            o[j] = fmaxf(acc, 0.f);
        }
        *(float4*)(hv + (size_t)n * 64 + dc * 8)     = make_float4(o[0], o[1], o[2], o[3]);
        *(float4*)(hv + (size_t)n * 64 + dc * 8 + 4) = make_float4(o[4], o[5], o[6], o[7]);
    }
    // --- w2rt (vectorized, 8 k/thread): t < 64*1024 ---
    if (t < 64 * 1024) {
        int o = t >> 10, kc = t & 1023;
        int k0 = kc * 8, i = k0 >> 7, h0 = k0 & 127;
        const float* src = w2 + (size_t)(i * 64 + o) * 128 + h0;
        const float4 a = *(const float4*)src;
        const float4 b = *(const float4*)(src + 4);
        half8 r = {(_Float16)a.x, (_Float16)a.y, (_Float16)a.z, (_Float16)a.w,
                   (_Float16)b.x, (_Float16)b.y, (_Float16)b.z, (_Float16)b.w};
        *(half8*)(W2rT + (size_t)o * 8192 + k0) = r;
    }
    // --- set2set weight transposes ---
    if (t < 256 * 128) { int j = t / 128, k = t % 128; lihT[k * 256 + j] = lih[t]; }
    if (t < 256 * 64) { int j = t / 64, k = t % 64; lhhT[k * 256 + j] = lhh[t]; }
    if (t < 64 * 128) { int d = t / 128, k = t % 128; l1T[k * 64 + d] = l1[t]; }
    // --- gru weight prep ---
    if (t < 64 * 128) {
        int n = t >> 7, k = t & 127;
        W1h[t] = (_Float16)(k < 64 ? root[k * 64 + n] : b2[(size_t)(k - 64) * 64 + n]);
    }
    if (t < 256 * 128) {
        int n2 = t >> 7, k = t & 127;
        int g = n2 >> 6, j = n2 & 63;
        float v;
        if (g == 0)      v = (k < 64) ? gwih[j * 64 + k]         : gwhh[j * 64 + (k - 64)];
        else if (g == 1) v = (k < 64) ? gwih[(64 + j) * 64 + k]  : gwhh[(64 + j) * 64 + (k - 64)];
        else if (g == 2) v = (k < 64) ? gwih[(128 + j) * 64 + k] : 0.f;
        else             v = (k < 64) ? 0.f                      : gwhh[(128 + j) * 64 + (k - 64)];
        W2h[t] = (_Float16)v;
    }
    if (t < 256) {
        int g = t >> 6, j = t & 63;
        float v = (g == 0) ? gbih[j] + gbhh[j]
                : (g == 1) ? gbih[64 + j] + gbhh[64 + j]
                : (g == 2) ? gbih[128 + j] : gbhh[128 + j];
        fbias[t] = v;
    }
}

// ---------------- msg GEMM: the verified 134us kernel (final) ----------------
// 256-edge tile, frag-order sB (zero conflicts), reg-staged double buffer,
// 1 barrier/slice, waves split on M only (M=64/wave, 16 B-frag reads : 64 MFMA).
// Six structural variants (L2-direct B, 32x32 MFMA, M=32/wave, split-K, DMA
// staging, M=128 @occ-1, 2-wave blocks) all measured slower -- this is the
// local optimum; remaining gap to the 66us MFMA floor is the 391-blocks-on-
// 512-slots packing (76%) + the 2-phase barrier stall (m233).
__global__ __launch_bounds__(256, 2) void msg_gemm_kernel(
    const float* __restrict__ hv, const _Float16* __restrict__ he16,
    const _Float16* __restrict__ W2rT, const int* __restrict__ ei,
    float* __restrict__ agg, float* __restrict__ xsum) {
    __shared__ _Float16 sB[2][16 * 64 * 8];   // [frag(nt*4+ks)][lane][8]
    __shared__ _Float16 sXs[256 * 68];        // [edge][i], padded stride 68
    __shared__ int sDst[256];
    const int t = threadIdx.x;
    const int eb = blockIdx.x * 256;
    const int lane = t & 63;
    const int w = t >> 6;
    const int col = lane & 15;
    const int quad = lane >> 4;

    if (t < 256) {
        int e = eb + t;
        sDst[t] = (e < EE) ? ei[EE + e] : 0;
    }
    #pragma unroll 4
    for (int rep = 0; rep < 16; rep++) {
        int idx = rep * 256 + t;
        int el = idx >> 4, d4 = idx & 15;
        int e = eb + el;
        float4 v = {0.f, 0.f, 0.f, 0.f};
        if (e < EE) {
            int src = ei[e];
            v = *(const float4*)(hv + (size_t)src * 64 + d4 * 4);
        }
        half4 h4 = {(_Float16)v.x, (_Float16)v.y, (_Float16)v.z, (_Float16)v.w};
        *(half4*)&sXs[el * 68 + d4 * 4] = h4;
    }

    half8 heReg[4][4];
    #pragma unroll
    for (int mt = 0; mt < 4; mt++) {
        int row = eb + w * 64 + mt * 16 + col;
        #pragma unroll
        for (int p = 0; p < 4; p++)
            heReg[mt][p] = *(const half8*)(he16 + (size_t)row * 128 + p * 32 + quad * 8);
    }

    floatx4 Cacc[4][4];
    #pragma unroll
    for (int mt = 0; mt < 4; mt++)
        #pragma unroll
        for (int nt = 0; nt < 4; nt++)
            Cacc[mt][nt] = (floatx4){0.f, 0.f, 0.f, 0.f};

    const size_t gbase = (size_t)(w * 16 + col) * 8192 + quad * 8;
    half8 pre[4];
    {
        #pragma unroll
        for (int rep = 0; rep < 4; rep++)
            pre[rep] = *(const half8*)(W2rT + gbase + 0 * 128 + rep * 32);
        #pragma unroll
        for (int rep = 0; rep < 4; rep++)
            *(half8*)&sB[0][((w * 4 + rep) * 64 + lane) * 8] = pre[rep];
    }
    __syncthreads();

    #pragma unroll 1
    for (int i = 0; i < 64; i++) {
        int buf = i & 1;
        if (i < 63) {
            #pragma unroll
            for (int rep = 0; rep < 4; rep++)
                pre[rep] = *(const half8*)(W2rT + gbase + (size_t)(i + 1) * 128 + rep * 32);
        }
        _Float16 xsx[4];
        #pragma unroll
        for (int mt = 0; mt < 4; mt++)
            xsx[mt] = sXs[(w * 64 + mt * 16 + col) * 68 + i];
        #pragma unroll
        for (int ks = 0; ks < 4; ks++) {
            half8 bfr[4];
            #pragma unroll
            for (int nt = 0; nt < 4; nt++)
                bfr[nt] = *(const half8*)&sB[buf][((nt * 4 + ks) * 64 + lane) * 8];
            #pragma unroll
            for (int mt = 0; mt < 4; mt++) {
                half8 afr = heReg[mt][ks] * xsx[mt];
                #pragma unroll
                for (int nt = 0; nt < 4; nt++)
                    Cacc[mt][nt] = __builtin_amdgcn_mfma_f32_16x16x32_f16(afr, bfr[nt], Cacc[mt][nt], 0, 0, 0);
            }
        }
        if (i < 63) {
            #pragma unroll
            for (int rep = 0; rep < 4; rep++)
                *(half8*)&sB[buf ^ 1][((w * 4 + rep) * 64 + lane) * 8] = pre[rep];
        }
        __syncthreads();
    }

    #pragma unroll
    for (int mt = 0; mt < 4; mt++) {
        #pragma unroll
        for (int r = 0; r < 4; r++) {
            int el = w * 64 + mt * 16 + quad * 4 + r;
            if (eb + el < EE) {
                float* ap = agg + (size_t)sDst[el] * 64 + col;
                #pragma unroll
                for (int nt = 0; nt < 4; nt++)
                    atomicAdd(ap + nt * 16, Cacc[mt][nt][r]);
            }
        }
    }
    #pragma unroll 4
    for (int rep = 0; rep < 64; rep++) {
        int idx = rep * 256 + t;
        int el = idx >> 6, d = idx & 63;
        if (eb + el < EE)
            atomicAdd(&xsum[(size_t)sDst[el] * 64 + d], (float)sXs[el * 68 + d]);
    }
}

// ---------------- fused node update: NNConv epilogue + GRU (MFMA) ----------------
// hold values prefetched into registers before the stage-2 MFMA block; direct global
// store of h_new (rows block-exclusive); re-zeros agg/xsum for the next msg launch.
__global__ __launch_bounds__(256, 3) void node_fused_kernel(
    const float* __restrict__ hv_in, float* __restrict__ agg,
    float* __restrict__ xsum, const float* __restrict__ deg,
    const _Float16* __restrict__ W1h, const _Float16* __restrict__ W2h,
    const float* __restrict__ fbias, const float* __restrict__ cb,
    float* __restrict__ hv_out) {
    __shared__ _Float16 sA1[64 * 136];  // [node][k]: k<64 hv, k>=64 xsum/deg
    __shared__ _Float16 sA2[64 * 136];  // [node][k]: k<64 m, k>=64 hv
    __shared__ float sAgg[64 * 68];     // agg/deg fp32
    const int t = threadIdx.x;
    const int nb = blockIdx.x * 64;
    const int n = t >> 2, part = t & 3;
    {
        int gn = nb + n;
        bool valid = gn < NN;
        float inv = 1.f;
        if (valid) inv = 1.f / fmaxf(deg[gn], 1.f);
        #pragma unroll
        for (int c4 = 0; c4 < 4; c4++) {
            int d0 = part * 16 + c4 * 4;
            float4 hvv = {0.f, 0.f, 0.f, 0.f}, agv = {0.f, 0.f, 0.f, 0.f}, xsv = {0.f, 0.f, 0.f, 0.f};
            if (valid) {
                hvv = *(const float4*)(hv_in + (size_t)gn * 64 + d0);
                agv = *(const float4*)(agg + (size_t)gn * 64 + d0);
                xsv = *(const float4*)(xsum + (size_t)gn * 64 + d0);
            }
            agv.x *= inv; agv.y *= inv; agv.z *= inv; agv.w *= inv;
            xsv.x *= inv; xsv.y *= inv; xsv.z *= inv; xsv.w *= inv;
            half4 hvh = {(_Float16)hvv.x, (_Float16)hvv.y, (_Float16)hvv.z, (_Float16)hvv.w};
            half4 xsh = {(_Float16)xsv.x, (_Float16)xsv.y, (_Float16)xsv.z, (_Float16)xsv.w};
            *(half4*)&sA1[n * 136 + d0] = hvh;
            *(half4*)&sA1[n * 136 + 64 + d0] = xsh;
            *(half4*)&sA2[n * 136 + 64 + d0] = hvh;
            *(float4*)&sAgg[n * 68 + d0] = agv;
        }
        // re-zero agg/xsum for the next msg_gemm launch
        if (valid) {
            float4 z = {0.f, 0.f, 0.f, 0.f};
            #pragma unroll
            for (int c4 = 0; c4 < 4; c4++) {
                int d0 = part * 16 + c4 * 4;
                *(float4*)(agg + (size_t)gn * 64 + d0) = z;
                *(float4*)(xsum + (size_t)gn * 64 + d0) = z;
            }
        }
    }
    __syncthreads();

    const int lane = t & 63, w = t >> 6;
    const int col = lane & 15, quad = lane >> 4;

    // ---- stage 1 ----
    floatx4 C1[4];
    #pragma unroll
    for (int nt = 0; nt < 4; nt++) {
        float b = cb[nt * 16 + col];
        C1[nt] = (floatx4){b, b, b, b};
    }
    #pragma unroll
    for (int ks = 0; ks < 4; ks++) {
        half8 a = *(const half8*)&sA1[(w * 16 + col) * 136 + ks * 32 + quad * 8];
        #pragma unroll
        for (int nt = 0; nt < 4; nt++) {
            half8 bfr = *(const half8*)(W1h + (size_t)(nt * 16 + col) * 128 + ks * 32 + quad * 8);
            C1[nt] = __builtin_amdgcn_mfma_f32_16x16x32_f16(a, bfr, C1[nt], 0, 0, 0);
        }
    }
    #pragma unroll
    for (int nt = 0; nt < 4; nt++) {
        #pragma unroll
        for (int r = 0; r < 4; r++) {
            int node = w * 16 + quad * 4 + r;
            int j = nt * 16 + col;
            float m = fmaxf(C1[nt][r] + sAgg[node * 68 + j], 0.f);
            sA2[node * 136 + j] = (_Float16)m;
        }
    }
    __syncthreads();

    // ---- hold prefetch (arrives during stage-2 MFMAs) ----
    float holdv[4][4];
    #pragma unroll
    for (int r = 0; r < 4; r++) {
        int node = w * 16 + quad * 4 + r;
        int gn2 = nb + node;
        #pragma unroll
        for (int jt = 0; jt < 4; jt++)
            holdv[r][jt] = (gn2 < NN) ? hv_in[(size_t)gn2 * 64 + jt * 16 + col] : 0.f;
    }

    // ---- stage 2 ----
    floatx4 C2[16];
    #pragma unroll
    for (int nt2 = 0; nt2 < 16; nt2++) {
        float b = fbias[nt2 * 16 + col];
        C2[nt2] = (floatx4){b, b, b, b};
    }
    #pragma unroll
    for (int ks = 0; ks < 4; ks++) {
        half8 a = *(const half8*)&sA2[(w * 16 + col) * 136 + ks * 32 + quad * 8];
        #pragma unroll
        for (int nt2 = 0; nt2 < 16; nt2++) {
            half8 bfr = *(const half8*)(W2h + (size_t)(nt2 * 16 + col) * 128 + ks * 32 + quad * 8);
            C2[nt2] = __builtin_amdgcn_mfma_f32_16x16x32_f16(a, bfr, C2[nt2], 0, 0, 0);
        }
    }
    // ---- GRU epilogue: registers only ----
    #pragma unroll
    for (int r = 0; r < 4; r++) {
        int node = w * 16 + quad * 4 + r;
        int gn2 = nb + node;
        if (gn2 < NN) {
            #pragma unroll
            for (int jt = 0; jt < 4; jt++) {
                int j = jt * 16 + col;
                float rr = sig_fast(C2[jt][r]);
                float zz = sig_fast(C2[4 + jt][r]);
                float ng = tanh_fast(C2[8 + jt][r] + rr * C2[12 + jt][r]);
                hv_out[(size_t)gn2 * 64 + j] = (1.f - zz) * ng + zz * holdv[r][jt];
            }
        }
    }
}

// ---------------- fused Set2Set (3 steps) + readout, one block per graph ----------------
__global__ __launch_bounds__(256) void set2set_kernel(
    const float* __restrict__ hv,
    const float* __restrict__ lihT, const float* __restrict__ lhhT,
    const float* __restrict__ l_bih, const float* __restrict__ l_bhh,
    const float* __restrict__ lin1T, const float* __restrict__ lin1_b,
    const float* __restrict__ lin2_w, const float* __restrict__ lin2_b,
    float* __restrict__ out) {
    __shared__ float outS[25 * 65];
    __shared__ float qs[128], qh[64], qc[64], gat[256], ew[32], aw[32], red[64];
    int g = blockIdx.x;
    int t = threadIdx.x;
    for (int p = t; p < 25 * 64; p += 256) {
        int j = p >> 6, i = p & 63;
        outS[j * 65 + i] = hv[(size_t)(g * 25 + j) * 64 + i];
    }
    if (t < 128) qs[t] = 0.f;
    if (t < 64) { qh[t] = 0.f; qc[t] = 0.f; }
    __syncthreads();
    for (int it = 0; it < 3; it++) {
        float acc = l_bih[t] + l_bhh[t];
        for (int k = 0; k < 128; k++) acc += qs[k] * lihT[k * 256 + t];
        for (int k = 0; k < 64; k++) acc += qh[k] * lhhT[k * 256 + t];
        gat[t] = acc;
        __syncthreads();
        if (t < 64) {
            float ig = sig_fast(gat[t]);
            float fg = sig_fast(gat[64 + t]);
            float gg = tanh_fast(gat[128 + t]);
            float og = sig_fast(gat[192 + t]);
            float c = fg * qc[t] + ig * gg;
            qc[t] = c;
            qh[t] = og * tanh_fast(c);
        }
        __syncthreads();
        if (t < 25) {
            float e = 0.f;
            for (int i = 0; i < 64; i++) e += outS[t * 65 + i] * qh[i];
            ew[t] = e;
        }
        __syncthreads();
        // wave-parallel softmax over the 25 graph nodes (lanes 0..31 of wave 0)
        if (t < 32) {
            float e = (t < 25) ? ew[t] : -1e30f;
            float mx = e;
            #pragma unroll
            for (int o = 16; o > 0; o >>= 1) mx = fmaxf(mx, __shfl_xor(mx, o, 32));
            float a = (t < 25) ? __expf(e - mx) : 0.f;
            float s = a;
            #pragma unroll
            for (int o = 16; o > 0; o >>= 1) s += __shfl_xor(s, o, 32);
            if (t < 25) aw[t] = a * rcp_fast(s);
        }
        __syncthreads();
        if (t < 64) {
            float r = 0.f;
            for (int j = 0; j < 25; j++) r += aw[j] * outS[j * 65 + t];
            qs[t] = qh[t];
            qs[64 + t] = r;
        }
        __syncthreads();
    }
    if (t < 64) {
        float y1 = lin1_b[t];
        for (int k = 0; k < 128; k++) y1 += qs[k] * lin1T[k * 64 + t];
        y1 = fmaxf(y1, 0.f);
        red[t] = y1 * lin2_w[t];
    }
    __syncthreads();
    if (t == 0) {
        float y = lin2_b[0];
        for (int i = 0; i < 64; i++) y += red[i];
        out[g] = y;
    }
}

extern "C" void kernel_launch(void* const* d_in, const int* in_sizes, int n_in,
                              void* d_out, int out_size, void* d_ws, size_t ws_size,
                              hipStream_t stream) {
    const float* x        = (const float*)d_in[0];
    const float* ea       = (const float*)d_in[1];
    const int*   ei       = (const int*)  d_in[2];
    const float* lin0_w   = (const float*)d_in[4];
    const float* lin0_b   = (const float*)d_in[5];
    const float* mlp_w1   = (const float*)d_in[6];
    const float* mlp_b1   = (const float*)d_in[7];
    const float* mlp_w2   = (const float*)d_in[8];
    const float* mlp_b2   = (const float*)d_in[9];
    const float* root     = (const float*)d_in[10];
    const float* conv_b   = (const float*)d_in[11];
    const float* gru_wih  = (const float*)d_in[12];
    const float* gru_whh  = (const float*)d_in[13];
    const float* gru_bih  = (const float*)d_in[14];
    const float* gru_bhh  = (const float*)d_in[15];
    const float* lstm_wih = (const float*)d_in[16];
    const float* lstm_whh = (const float*)d_in[17];
    const float* lstm_bih = (const float*)d_in[18];
    const float* lstm_bhh = (const float*)d_in[19];
    const float* lin1_w   = (const float*)d_in[20];
    const float* lin1_b   = (const float*)d_in[21];
    const float* lin2_w   = (const float*)d_in[22];
    const float* lin2_b   = (const float*)d_in[23];
    float* out = (float*)d_out;

    // ---- workspace carve ----
    char* base = (char*)d_ws;
    size_t off = 0;
    auto carve = [&](size_t bytes) -> void* {
        void* r = base + off;
        off = (off + bytes + 255) & ~(size_t)255;
        return r;
    };
    float* hv   = (float*)carve((size_t)NN * 64 * 4);
    float* agg  = (float*)carve((size_t)NN * 64 * 4);   // agg+xsum adjacent (one zero-init)
    float* xsum = (float*)carve((size_t)NN * 64 * 4);
    float* deg  = (float*)carve((size_t)NN * 4);
    float* lihT = (float*)carve(128 * 256 * 4);
    float* lhhT = (float*)carve(64 * 256 * 4);
    float* l1T  = (float*)carve(128 * 64 * 4);
    float* fbias = (float*)carve(256 * 4);
    _Float16* he16 = (_Float16*)carve((size_t)EPAD2 * 128 * 2);
    _Float16* W2rT = (_Float16*)carve((size_t)64 * 8192 * 2);
    _Float16* W1h  = (_Float16*)carve((size_t)64 * 128 * 2);
    _Float16* W2h  = (_Float16*)carve((size_t)256 * 128 * 2);

    // ---- preamble: tiny deg memset + one fused prep kernel (zeros agg/xsum itself) ----
    hipMemsetAsync(deg, 0, (size_t)NN * 4, stream);
    prep_fused_kernel<<<EPAD2 * 16 / 256, 256, 0, stream>>>(
        x, lin0_w, lin0_b, hv,
        ea, mlp_w1, mlp_b1, he16, ei, deg,
        mlp_w2, W2rT,
        lstm_wih, lstm_whh, lin1_w, lihT, lhhT, l1T,
        root, mlp_b2, gru_wih, gru_whh, gru_bih, gru_bhh,
        W1h, W2h, fbias, agg);

    // ---- 3 message-passing + GRU iterations (node_fused re-zeros agg/xsum) ----
    for (int it = 0; it < 3; it++) {
        msg_gemm_kernel<<<EPAD / 256, 256, 0, stream>>>(hv, he16, W2rT, ei, agg, xsum);
        node_fused_kernel<<<(NN + 63) / 64, 256, 0, stream>>>(hv, agg, xsum, deg,
                                                              W1h, W2h, fbias, conv_b, hv);
    }

    // ---- Set2Set + readout ----
    set2set_kernel<<<BB, 256, 0, stream>>>(hv, lihT, lhhT, lstm_bih, lstm_bhh,
                                           l1T, lin1_b, lin2_w, lin2_b, out);
}

// Round 11
// 727.079 us; speedup vs baseline: 1.1405x; 1.0181x over previous
//
#include <hip/hip_runtime.h>
#include <hip/hip_bf16.h>

#define NN 50000
#define EE 100000
#define BB 2000
#define DIM 64
#define NF 14
#define EF 4
#define HID 128
#define EPAD 100096   // 391*256 (msg tile grid)
#define EPAD2 100352  // he16 padded allocation

typedef __attribute__((ext_vector_type(8))) _Float16 half8;   // 4 VGPRs
typedef __attribute__((ext_vector_type(4))) _Float16 half4;
typedef __attribute__((ext_vector_type(4))) float floatx4;    // MFMA C/D

__device__ __forceinline__ float rcp_fast(float x) { return __builtin_amdgcn_rcpf(x); }
__device__ __forceinline__ float sig_fast(float x) { return rcp_fast(1.f + __expf(-x)); }
__device__ __forceinline__ float tanh_fast(float x) {
    float e = __expf(2.f * x);
    return 1.f - 2.f * rcp_fast(e + 1.f);
}

// ---------------- fused preamble: w2rt + transposes + gru-prep + he16(+deg) + lin0 ----
__global__ void prep_fused_kernel(
    const float* __restrict__ x, const float* __restrict__ lin0_w,
    const float* __restrict__ lin0_b, float* __restrict__ hv,
    const float* __restrict__ ea, const float* __restrict__ w1,
    const float* __restrict__ b1, _Float16* __restrict__ he,
    const int* __restrict__ ei, float* __restrict__ deg,
    const float* __restrict__ w2, _Float16* __restrict__ W2rT,
    const float* __restrict__ lih, const float* __restrict__ lhh,
    const float* __restrict__ l1, float* __restrict__ lihT,
    float* __restrict__ lhhT, float* __restrict__ l1T,
    const float* __restrict__ root, const float* __restrict__ b2,
    const float* __restrict__ gwih, const float* __restrict__ gwhh,
    const float* __restrict__ gbih, const float* __restrict__ gbhh,
    _Float16* __restrict__ W1h, _Float16* __restrict__ W2h,
    float* __restrict__ fbias) {
    int t = blockIdx.x * 256 + threadIdx.x;

    // --- he16 (vectorized, 8 h/thread) + deg atomic; rows >= EE zero-padded ---
    {
        int el = t >> 4, hc = t & 15;
        if (el < EPAD2) {
            half8 o8 = {0, 0, 0, 0, 0, 0, 0, 0};
            if (el < EE) {
                const float4 a = *(const float4*)(ea + (size_t)el * 4);
                #pragma unroll
                for (int j = 0; j < 8; j++) {
                    int h = hc * 8 + j;
                    const float4 w = *(const float4*)(w1 + h * 4);
                    float acc = fmaxf(b1[h] + a.x * w.x + a.y * w.y + a.z * w.z + a.w * w.w, 0.f);
                    o8[j] = (_Float16)acc;
                }
                if (hc == 0) atomicAdd(&deg[ei[EE + el]], 1.0f);
            }
            *(half8*)(he + (size_t)el * 128 + hc * 8) = o8;
        }
    }
    // --- lin0 (vectorized, 8 d/thread): t < NN*8 ---
    if (t < NN * 8) {
        int n = t >> 3, dc = t & 7;
        float xv[NF];
        #pragma unroll
        for (int f = 0; f < NF; f++) xv[f] = x[(size_t)n * NF + f];
        float o[8];
        #pragma unroll
        for (int j = 0; j < 8; j++) {
            int d = dc * 8 + j;
            float acc = lin0_b[d];
            #pragma unroll
            for (int f = 0; f < NF; f++) acc += xv[f] * lin0_w[d * NF + f];
            o[j] = fmaxf(acc, 0.f);
        }
        *(float4*)(hv + (size_t)n * 64 + dc * 8)     = make_float4(o[0], o[1], o[2], o[3]);
        *(float4*)(hv + (size_t)n * 64 + dc * 8 + 4) = make_float4(o[4], o[5], o[6], o[7]);
    }
    // --- w2rt (vectorized, 8 k/thread): t < 64*1024 ---
    if (t < 64 * 1024) {
        int o = t >> 10, kc = t & 1023;
        int k0 = kc * 8, i = k0 >> 7, h0 = k0 & 127;
        const float* src = w2 + (size_t)(i * 64 + o) * 128 + h0;
        const float4 a = *(const float4*)src;
        const float4 b = *(const float4*)(src + 4);
        half8 r = {(_Float16)a.x, (_Float16)a.y, (_Float16)a.z, (_Float16)a.w,
                   (_Float16)b.x, (_Float16)b.y, (_Float16)b.z, (_Float16)b.w};
        *(half8*)(W2rT + (size_t)o * 8192 + k0) = r;
    }
    // --- set2set weight transposes ---
    if (t < 256 * 128) { int j = t / 128, k = t % 128; lihT[k * 256 + j] = lih[t]; }
    if (t < 256 * 64) { int j = t / 64, k = t % 64; lhhT[k * 256 + j] = lhh[t]; }
    if (t < 64 * 128) { int d = t / 128, k = t % 128; l1T[k * 64 + d] = l1[t]; }
    // --- gru weight prep ---
    if (t < 64 * 128) {
        int n = t >> 7, k = t & 127;
        W1h[t] = (_Float16)(k < 64 ? root[k * 64 + n] : b2[(size_t)(k - 64) * 64 + n]);
    }
    if (t < 256 * 128) {
        int n2 = t >> 7, k = t & 127;
        int g = n2 >> 6, j = n2 & 63;
        float v;
        if (g == 0)      v = (k < 64) ? gwih[j * 64 + k]         : gwhh[j * 64 + (k - 64)];
        else if (g == 1) v = (k < 64) ? gwih[(64 + j) * 64 + k]  : gwhh[(64 + j) * 64 + (k - 64)];
        else if (g == 2) v = (k < 64) ? gwih[(128 + j) * 64 + k] : 0.f;
        else             v = (k < 64) ? 0.f                      : gwhh[(128 + j) * 64 + (k - 64)];
        W2h[t] = (_Float16)v;
    }
    if (t < 256) {
        int g = t >> 6, j = t & 63;
        float v = (g == 0) ? gbih[j] + gbhh[j]
                : (g == 1) ? gbih[64 + j] + gbhh[64 + j]
                : (g == 2) ? gbih[128 + j] : gbhh[128 + j];
        fbias[t] = v;
    }
}

// ---------------- msg GEMM: the verified 134us kernel (final; no setprio) ------------
// 256-edge tile, frag-order sB (zero conflicts), reg-staged double buffer,
// 1 barrier/slice, waves split on M only (M=64/wave, 16 B-frag reads : 64 MFMA).
// Seven structural variants (L2-direct B, 32x32 MFMA, M=32/wave, split-K, DMA
// staging, M=128 @occ-1, 2-wave blocks, setprio) all measured slower or neutral --
// this is the local optimum; remaining gap to the MFMA floor is the 391-blocks-on-
// 512-slots packing (76%) + the 2-phase barrier stall (m233).
__global__ __launch_bounds__(256, 2) void msg_gemm_kernel(
    const float* __restrict__ hv, const _Float16* __restrict__ he16,
    const _Float16* __restrict__ W2rT, const int* __restrict__ ei,
    float* __restrict__ agg, float* __restrict__ xsum) {
    __shared__ _Float16 sB[2][16 * 64 * 8];   // [frag(nt*4+ks)][lane][8]
    __shared__ _Float16 sXs[256 * 68];        // [edge][i], padded stride 68
    __shared__ int sDst[256];
    const int t = threadIdx.x;
    const int eb = blockIdx.x * 256;
    const int lane = t & 63;
    const int w = t >> 6;
    const int col = lane & 15;
    const int quad = lane >> 4;

    if (t < 256) {
        int e = eb + t;
        sDst[t] = (e < EE) ? ei[EE + e] : 0;
    }
    #pragma unroll 4
    for (int rep = 0; rep < 16; rep++) {
        int idx = rep * 256 + t;
        int el = idx >> 4, d4 = idx & 15;
        int e = eb + el;
        float4 v = {0.f, 0.f, 0.f, 0.f};
        if (e < EE) {
            int src = ei[e];
            v = *(const float4*)(hv + (size_t)src * 64 + d4 * 4);
        }
        half4 h4 = {(_Float16)v.x, (_Float16)v.y, (_Float16)v.z, (_Float16)v.w};
        *(half4*)&sXs[el * 68 + d4 * 4] = h4;
    }

    half8 heReg[4][4];
    #pragma unroll
    for (int mt = 0; mt < 4; mt++) {
        int row = eb + w * 64 + mt * 16 + col;
        #pragma unroll
        for (int p = 0; p < 4; p++)
            heReg[mt][p] = *(const half8*)(he16 + (size_t)row * 128 + p * 32 + quad * 8);
    }

    floatx4 Cacc[4][4];
    #pragma unroll
    for (int mt = 0; mt < 4; mt++)
        #pragma unroll
        for (int nt = 0; nt < 4; nt++)
            Cacc[mt][nt] = (floatx4){0.f, 0.f, 0.f, 0.f};

    const size_t gbase = (size_t)(w * 16 + col) * 8192 + quad * 8;
    half8 pre[4];
    {
        #pragma unroll
        for (int rep = 0; rep < 4; rep++)
            pre[rep] = *(const half8*)(W2rT + gbase + 0 * 128 + rep * 32);
        #pragma unroll
        for (int rep = 0; rep < 4; rep++)
            *(half8*)&sB[0][((w * 4 + rep) * 64 + lane) * 8] = pre[rep];
    }
    __syncthreads();

    #pragma unroll 1
    for (int i = 0; i < 64; i++) {
        int buf = i & 1;
        if (i < 63) {
            #pragma unroll
            for (int rep = 0; rep < 4; rep++)
                pre[rep] = *(const half8*)(W2rT + gbase + (size_t)(i + 1) * 128 + rep * 32);
        }
        _Float16 xsx[4];
        #pragma unroll
        for (int mt = 0; mt < 4; mt++)
            xsx[mt] = sXs[(w * 64 + mt * 16 + col) * 68 + i];
        #pragma unroll
        for (int ks = 0; ks < 4; ks++) {
            half8 bfr[4];
            #pragma unroll
            for (int nt = 0; nt < 4; nt++)
                bfr[nt] = *(const half8*)&sB[buf][((nt * 4 + ks) * 64 + lane) * 8];
            #pragma unroll
            for (int mt = 0; mt < 4; mt++) {
                half8 afr = heReg[mt][ks] * xsx[mt];
                #pragma unroll
                for (int nt = 0; nt < 4; nt++)
                    Cacc[mt][nt] = __builtin_amdgcn_mfma_f32_16x16x32_f16(afr, bfr[nt], Cacc[mt][nt], 0, 0, 0);
            }
        }
        if (i < 63) {
            #pragma unroll
            for (int rep = 0; rep < 4; rep++)
                *(half8*)&sB[buf ^ 1][((w * 4 + rep) * 64 + lane) * 8] = pre[rep];
        }
        __syncthreads();
    }

    #pragma unroll
    for (int mt = 0; mt < 4; mt++) {
        #pragma unroll
        for (int r = 0; r < 4; r++) {
            int el = w * 64 + mt * 16 + quad * 4 + r;
            if (eb + el < EE) {
                float* ap = agg + (size_t)sDst[el] * 64 + col;
                #pragma unroll
                for (int nt = 0; nt < 4; nt++)
                    atomicAdd(ap + nt * 16, Cacc[mt][nt][r]);
            }
        }
    }
    #pragma unroll 4
    for (int rep = 0; rep < 64; rep++) {
        int idx = rep * 256 + t;
        int el = idx >> 6, d = idx & 63;
        if (eb + el < EE)
            atomicAdd(&xsum[(size_t)sDst[el] * 64 + d], (float)sXs[el * 68 + d]);
    }
}

// ---------------- fused node update: NNConv epilogue + GRU (MFMA) ----------------
// sH LDS round-trip removed (round-7 verified config): epilogue reads hold directly
// from hv_in (L2-hot) and stores h_new straight to hv_out (rows block-exclusive).
// LDS 52.2KB -> 3 blocks/CU. Re-zeros agg/xsum for the next msg launch.
__global__ __launch_bounds__(256, 3) void node_fused_kernel(
    const float* __restrict__ hv_in, float* __restrict__ agg,
    float* __restrict__ xsum, const float* __restrict__ deg,
    const _Float16* __restrict__ W1h, const _Float16* __restrict__ W2h,
    const float* __restrict__ fbias, const float* __restrict__ cb,
    float* __restrict__ hv_out) {
    __shared__ _Float16 sA1[64 * 136];  // [node][k]: k<64 hv, k>=64 xsum/deg
    __shared__ _Float16 sA2[64 * 136];  // [node][k]: k<64 m, k>=64 hv
    __shared__ float sAgg[64 * 68];     // agg/deg fp32
    const int t = threadIdx.x;
    const int nb = blockIdx.x * 64;
    const int n = t >> 2, part = t & 3;
    {
        int gn = nb + n;
        bool valid = gn < NN;
        float inv = 1.f;
        if (valid) inv = 1.f / fmaxf(deg[gn], 1.f);
        #pragma unroll
        for (int c4 = 0; c4 < 4; c4++) {
            int d0 = part * 16 + c4 * 4;
            float4 hvv = {0.f, 0.f, 0.f, 0.f}, agv = {0.f, 0.f, 0.f, 0.f}, xsv = {0.f, 0.f, 0.f, 0.f};
            if (valid) {
                hvv = *(const float4*)(hv_in + (size_t)gn * 64 + d0);
                agv = *(const float4*)(agg + (size_t)gn * 64 + d0);
                xsv = *(const float4*)(xsum + (size_t)gn * 64 + d0);
            }
            agv.x *= inv; agv.y *= inv; agv.z *= inv; agv.w *= inv;
            xsv.x *= inv; xsv.y *= inv; xsv.z *= inv; xsv.w *= inv;
            half4 hvh = {(_Float16)hvv.x, (_Float16)hvv.y, (_Float16)hvv.z, (_Float16)hvv.w};
            half4 xsh = {(_Float16)xsv.x, (_Float16)xsv.y, (_Float16)xsv.z, (_Float16)xsv.w};
            *(half4*)&sA1[n * 136 + d0] = hvh;
            *(half4*)&sA1[n * 136 + 64 + d0] = xsh;
            *(half4*)&sA2[n * 136 + 64 + d0] = hvh;
            *(float4*)&sAgg[n * 68 + d0] = agv;
        }
        // re-zero agg/xsum for the next msg_gemm launch
        if (valid) {
            float4 z = {0.f, 0.f, 0.f, 0.f};
            #pragma unroll
            for (int c4 = 0; c4 < 4; c4++) {
                int d0 = part * 16 + c4 * 4;
                *(float4*)(agg + (size_t)gn * 64 + d0) = z;
                *(float4*)(xsum + (size_t)gn * 64 + d0) = z;
            }
        }
    }
    __syncthreads();

    const int lane = t & 63, w = t >> 6;
    const int col = lane & 15, quad = lane >> 4;

    // ---- stage 1 ----
    floatx4 C1[4];
    #pragma unroll
    for (int nt = 0; nt < 4; nt++) {
        float b = cb[nt * 16 + col];
        C1[nt] = (floatx4){b, b, b, b};
    }
    #pragma unroll
    for (int ks = 0; ks < 4; ks++) {
        half8 a = *(const half8*)&sA1[(w * 16 + col) * 136 + ks * 32 + quad * 8];
        #pragma unroll
        for (int nt = 0; nt < 4; nt++) {
            half8 bfr = *(const half8*)(W1h + (size_t)(nt * 16 + col) * 128 + ks * 32 + quad * 8);
            C1[nt] = __builtin_amdgcn_mfma_f32_16x16x32_f16(a, bfr, C1[nt], 0, 0, 0);
        }
    }
    #pragma unroll
    for (int nt = 0; nt < 4; nt++) {
        #pragma unroll
        for (int r = 0; r < 4; r++) {
            int node = w * 16 + quad * 4 + r;
            int j = nt * 16 + col;
            float m = fmaxf(C1[nt][r] + sAgg[node * 68 + j], 0.f);
            sA2[node * 136 + j] = (_Float16)m;
        }
    }
    __syncthreads();

    // ---- stage 2 ----
    floatx4 C2[16];
    #pragma unroll
    for (int nt2 = 0; nt2 < 16; nt2++) {
        float b = fbias[nt2 * 16 + col];
        C2[nt2] = (floatx4){b, b, b, b};
    }
    #pragma unroll
    for (int ks = 0; ks < 4; ks++) {
        half8 a = *(const half8*)&sA2[(w * 16 + col) * 136 + ks * 32 + quad * 8];
        #pragma unroll
        for (int nt2 = 0; nt2 < 16; nt2++) {
            half8 bfr = *(const half8*)(W2h + (size_t)(nt2 * 16 + col) * 128 + ks * 32 + quad * 8);
            C2[nt2] = __builtin_amdgcn_mfma_f32_16x16x32_f16(a, bfr, C2[nt2], 0, 0, 0);
        }
    }
    // ---- GRU epilogue: direct global hold-read + store (no sH round-trip) ----
    #pragma unroll
    for (int r = 0; r < 4; r++) {
        int node = w * 16 + quad * 4 + r;
        int gn2 = nb + node;
        if (gn2 < NN) {
            #pragma unroll
            for (int jt = 0; jt < 4; jt++) {
                int j = jt * 16 + col;
                float rr = sig_fast(C2[jt][r]);
                float zz = sig_fast(C2[4 + jt][r]);
                float ng = tanh_fast(C2[8 + jt][r] + rr * C2[12 + jt][r]);
                float hold = hv_in[(size_t)gn2 * 64 + j];
                hv_out[(size_t)gn2 * 64 + j] = (1.f - zz) * ng + zz * hold;
            }
        }
    }
}

// ---------------- fused Set2Set (3 steps) + readout, one block per graph ----------------
__global__ __launch_bounds__(256) void set2set_kernel(
    const float* __restrict__ hv,
    const float* __restrict__ lihT, const float* __restrict__ lhhT,
    const float* __restrict__ l_bih, const float* __restrict__ l_bhh,
    const float* __restrict__ lin1T, const float* __restrict__ lin1_b,
    const float* __restrict__ lin2_w, const float* __restrict__ lin2_b,
    float* __restrict__ out) {
    __shared__ float outS[25 * 65];
    __shared__ float qs[128], qh[64], qc[64], gat[256], ew[32], aw[32], red[64];
    int g = blockIdx.x;
    int t = threadIdx.x;
    for (int p = t; p < 25 * 64; p += 256) {
        int j = p >> 6, i = p & 63;
        outS[j * 65 + i] = hv[(size_t)(g * 25 + j) * 64 + i];
    }
    if (t < 128) qs[t] = 0.f;
    if (t < 64) { qh[t] = 0.f; qc[t] = 0.f; }
    __syncthreads();
    for (int it = 0; it < 3; it++) {
        float acc = l_bih[t] + l_bhh[t];
        for (int k = 0; k < 128; k++) acc += qs[k] * lihT[k * 256 + t];
        for (int k = 0; k < 64; k++) acc += qh[k] * lhhT[k * 256 + t];
        gat[t] = acc;
        __syncthreads();
        if (t < 64) {
            float ig = sig_fast(gat[t]);
            float fg = sig_fast(gat[64 + t]);
            float gg = tanh_fast(gat[128 + t]);
            float og = sig_fast(gat[192 + t]);
            float c = fg * qc[t] + ig * gg;
            qc[t] = c;
            qh[t] = og * tanh_fast(c);
        }
        __syncthreads();
        if (t < 25) {
            float e = 0.f;
            for (int i = 0; i < 64; i++) e += outS[t * 65 + i] * qh[i];
            ew[t] = e;
        }
        __syncthreads();
        // wave-parallel softmax over the 25 graph nodes (lanes 0..31 of wave 0)
        if (t < 32) {
            float e = (t < 25) ? ew[t] : -1e30f;
            float mx = e;
            #pragma unroll
            for (int o = 16; o > 0; o >>= 1) mx = fmaxf(mx, __shfl_xor(mx, o, 32));
            float a = (t < 25) ? __expf(e - mx) : 0.f;
            float s = a;
            #pragma unroll
            for (int o = 16; o > 0; o >>= 1) s += __shfl_xor(s, o, 32);
            if (t < 25) aw[t] = a * rcp_fast(s);
        }
        __syncthreads();
        if (t < 64) {
            float r = 0.f;
            for (int j = 0; j < 25; j++) r += aw[j] * outS[j * 65 + t];
            qs[t] = qh[t];
            qs[64 + t] = r;
        }
        __syncthreads();
    }
    if (t < 64) {
        float y1 = lin1_b[t];
        for (int k = 0; k < 128; k++) y1 += qs[k] * lin1T[k * 64 + t];
        y1 = fmaxf(y1, 0.f);
        red[t] = y1 * lin2_w[t];
    }
    __syncthreads();
    if (t == 0) {
        float y = lin2_b[0];
        for (int i = 0; i < 64; i++) y += red[i];
        out[g] = y;
    }
}

extern "C" void kernel_launch(void* const* d_in, const int* in_sizes, int n_in,
                              void* d_out, int out_size, void* d_ws, size_t ws_size,
                              hipStream_t stream) {
    const float* x        = (const float*)d_in[0];
    const float* ea       = (const float*)d_in[1];
    const int*   ei       = (const int*)  d_in[2];
    const float* lin0_w   = (const float*)d_in[4];
    const float* lin0_b   = (const float*)d_in[5];
    const float* mlp_w1   = (const float*)d_in[6];
    const float* mlp_b1   = (const float*)d_in[7];
    const float* mlp_w2   = (const float*)d_in[8];
    const float* mlp_b2   = (const float*)d_in[9];
    const float* root     = (const float*)d_in[10];
    const float* conv_b   = (const float*)d_in[11];
    const float* gru_wih  = (const float*)d_in[12];
    const float* gru_whh  = (const float*)d_in[13];
    const float* gru_bih  = (const float*)d_in[14];
    const float* gru_bhh  = (const float*)d_in[15];
    const float* lstm_wih = (const float*)d_in[16];
    const float* lstm_whh = (const float*)d_in[17];
    const float* lstm_bih = (const float*)d_in[18];
    const float* lstm_bhh = (const float*)d_in[19];
    const float* lin1_w   = (const float*)d_in[20];
    const float* lin1_b   = (const float*)d_in[21];
    const float* lin2_w   = (const float*)d_in[22];
    const float* lin2_b   = (const float*)d_in[23];
    float* out = (float*)d_out;

    // ---- workspace carve ----
    char* base = (char*)d_ws;
    size_t off = 0;
    auto carve = [&](size_t bytes) -> void* {
        void* r = base + off;
        off = (off + bytes + 255) & ~(size_t)255;
        return r;
    };
    float* hv   = (float*)carve((size_t)NN * 64 * 4);
    float* agg  = (float*)carve((size_t)NN * 64 * 4);   // agg+xsum+deg adjacent: one memset
    float* xsum = (float*)carve((size_t)NN * 64 * 4);
    float* deg  = (float*)carve((size_t)NN * 4);
    float* lihT = (float*)carve(128 * 256 * 4);
    float* lhhT = (float*)carve(64 * 256 * 4);
    float* l1T  = (float*)carve(128 * 64 * 4);
    float* fbias = (float*)carve(256 * 4);
    _Float16* he16 = (_Float16*)carve((size_t)EPAD2 * 128 * 2);
    _Float16* W2rT = (_Float16*)carve((size_t)64 * 8192 * 2);
    _Float16* W1h  = (_Float16*)carve((size_t)64 * 128 * 2);
    _Float16* W2h  = (_Float16*)carve((size_t)256 * 128 * 2);

    // ---- preamble: one memset (agg+xsum+deg contiguous) + one fused prep kernel ----
    hipMemsetAsync(agg, 0, (size_t)NN * 64 * 4 * 2 + (size_t)NN * 4, stream);
    prep_fused_kernel<<<EPAD2 * 16 / 256, 256, 0, stream>>>(
        x, lin0_w, lin0_b, hv,
        ea, mlp_w1, mlp_b1, he16, ei, deg,
        mlp_w2, W2rT,
        lstm_wih, lstm_whh, lin1_w, lihT, lhhT, l1T,
        root, mlp_b2, gru_wih, gru_whh, gru_bih, gru_bhh,
        W1h, W2h, fbias);

    // ---- 3 message-passing + GRU iterations (node_fused re-zeros agg/xsum) ----
    for (int it = 0; it < 3; it++) {
        msg_gemm_kernel<<<EPAD / 256, 256, 0, stream>>>(hv, he16, W2rT, ei, agg, xsum);
        node_fused_kernel<<<(NN + 63) / 64, 256, 0, stream>>>(hv, agg, xsum, deg,
                                                              W1h, W2h, fbias, conv_b, hv);
    }

    // ---- Set2Set + readout ----
    set2set_kernel<<<BB, 256, 0, stream>>>(hv, lihT, lhhT, lstm_bih, lstm_bhh,
                                           l1T, lin1_b, lin2_w, lin2_b, out);
}

// Round 12
// 723.913 us; speedup vs baseline: 1.1455x; 1.0044x over previous
//
#include <hip/hip_runtime.h>
#include <hip/hip_bf16.h>

#define NN 50000
#define EE 100000
#define BB 2000
#define DIM 64
#define NF 14
#define EF 4
#define HID 128
#define EPAD 100096   // 391*256 (msg tile grid)
#define EPAD2 100352  // he16 padded allocation

typedef __attribute__((ext_vector_type(8))) _Float16 half8;   // 4 VGPRs
typedef __attribute__((ext_vector_type(4))) _Float16 half4;
typedef __attribute__((ext_vector_type(4))) float floatx4;    // MFMA C/D (16x16)
typedef __attribute__((ext_vector_type(16))) float floatx16;  // MFMA C/D (32x32)

__device__ __forceinline__ float rcp_fast(float x) { return __builtin_amdgcn_rcpf(x); }
__device__ __forceinline__ float sig_fast(float x) { return rcp_fast(1.f + __expf(-x)); }
__device__ __forceinline__ float tanh_fast(float x) {
    float e = __expf(2.f * x);
    return 1.f - 2.f * rcp_fast(e + 1.f);
}

// ---------------- fused preamble: w2rt + transposes + gru-prep + he16(+deg) + lin0 ----
__global__ void prep_fused_kernel(
    const float* __restrict__ x, const float* __restrict__ lin0_w,
    const float* __restrict__ lin0_b, float* __restrict__ hv,
    const float* __restrict__ ea, const float* __restrict__ w1,
    const float* __restrict__ b1, _Float16* __restrict__ he,
    const int* __restrict__ ei, float* __restrict__ deg,
    const float* __restrict__ w2, _Float16* __restrict__ W2rT,
    const float* __restrict__ lih, const float* __restrict__ lhh,
    const float* __restrict__ l1, float* __restrict__ lihT,
    float* __restrict__ lhhT, float* __restrict__ l1T,
    const float* __restrict__ root, const float* __restrict__ b2,
    const float* __restrict__ gwih, const float* __restrict__ gwhh,
    const float* __restrict__ gbih, const float* __restrict__ gbhh,
    _Float16* __restrict__ W1h, _Float16* __restrict__ W2h,
    float* __restrict__ fbias) {
    int t = blockIdx.x * 256 + threadIdx.x;

    // --- he16 (vectorized, 8 h/thread) + deg atomic; rows >= EE zero-padded ---
    {
        int el = t >> 4, hc = t & 15;
        if (el < EPAD2) {
            half8 o8 = {0, 0, 0, 0, 0, 0, 0, 0};
            if (el < EE) {
                const float4 a = *(const float4*)(ea + (size_t)el * 4);
                #pragma unroll
                for (int j = 0; j < 8; j++) {
                    int h = hc * 8 + j;
                    const float4 w = *(const float4*)(w1 + h * 4);
                    float acc = fmaxf(b1[h] + a.x * w.x + a.y * w.y + a.z * w.z + a.w * w.w, 0.f);
                    o8[j] = (_Float16)acc;
                }
                if (hc == 0) atomicAdd(&deg[ei[EE + el]], 1.0f);
            }
            *(half8*)(he + (size_t)el * 128 + hc * 8) = o8;
        }
    }
    // --- lin0 (vectorized, 8 d/thread): t < NN*8 ---
    if (t < NN * 8) {
        int n = t >> 3, dc = t & 7;
        float xv[NF];
        #pragma unroll
        for (int f = 0; f < NF; f++) xv[f] = x[(size_t)n * NF + f];
        float o[8];
        #pragma unroll
        for (int j = 0; j < 8; j++) {
            int d = dc * 8 + j;
            float acc = lin0_b[d];
            #pragma unroll
            for (int f = 0; f < NF; f++) acc += xv[f] * lin0_w[d * NF + f];
            o[j] = fmaxf(acc, 0.f);
        }
        *(float4*)(hv + (size_t)n * 64 + dc * 8)     = make_float4(o[0], o[1], o[2], o[3]);
        *(float4*)(hv + (size_t)n * 64 + dc * 8 + 4) = make_float4(o[4], o[5], o[6], o[7]);
    }
    // --- w2rt (vectorized, 8 k/thread): t < 64*1024 ---
    if (t < 64 * 1024) {
        int o = t >> 10, kc = t & 1023;
        int k0 = kc * 8, i = k0 >> 7, h0 = k0 & 127;
        const float* src = w2 + (size_t)(i * 64 + o) * 128 + h0;
        const float4 a = *(const float4*)src;
        const float4 b = *(const float4*)(src + 4);
        half8 r = {(_Float16)a.x, (_Float16)a.y, (_Float16)a.z, (_Float16)a.w,
                   (_Float16)b.x, (_Float16)b.y, (_Float16)b.z, (_Float16)b.w};
        *(half8*)(W2rT + (size_t)o * 8192 + k0) = r;
    }
    // --- set2set weight transposes ---
    if (t < 256 * 128) { int j = t / 128, k = t % 128; lihT[k * 256 + j] = lih[t]; }
    if (t < 256 * 64) { int j = t / 64, k = t % 64; lhhT[k * 256 + j] = lhh[t]; }
    if (t < 64 * 128) { int d = t / 128, k = t % 128; l1T[k * 64 + d] = l1[t]; }
    // --- gru weight prep ---
    if (t < 64 * 128) {
        int n = t >> 7, k = t & 127;
        W1h[t] = (_Float16)(k < 64 ? root[k * 64 + n] : b2[(size_t)(k - 64) * 64 + n]);
    }
    if (t < 256 * 128) {
        int n2 = t >> 7, k = t & 127;
        int g = n2 >> 6, j = n2 & 63;
        float v;
        if (g == 0)      v = (k < 64) ? gwih[j * 64 + k]         : gwhh[j * 64 + (k - 64)];
        else if (g == 1) v = (k < 64) ? gwih[(64 + j) * 64 + k]  : gwhh[(64 + j) * 64 + (k - 64)];
        else if (g == 2) v = (k < 64) ? gwih[(128 + j) * 64 + k] : 0.f;
        else             v = (k < 64) ? 0.f                      : gwhh[(128 + j) * 64 + (k - 64)];
        W2h[t] = (_Float16)v;
    }
    if (t < 256) {
        int g = t >> 6, j = t & 63;
        float v = (g == 0) ? gbih[j] + gbhh[j]
                : (g == 1) ? gbih[64 + j] + gbhh[64 + j]
                : (g == 2) ? gbih[128 + j] : gbhh[128 + j];
        fbias[t] = v;
    }
}

// ---------------- msg GEMM: champion dataflow, 32x32x16 MFMA, M-only wave split ------
// Identical to the verified 134us kernel in every pipe EXCEPT the MFMA shape:
//   - wave w owns edges [w*64, w*64+64) as 2 tiles of 32 rows (M-only split --
//     round 1's regression came from the 2x2 wm*wn split doubling A-construction
//     VALU, NOT from the shape);
//   - per wave per slice: 16 afr mults (same), 16 b128 B-reads (same), 4 staged
//     frags (same), but 32 MFMA x 8.07cyc = 258 cyc vs 64 x 4.85 = 310 cyc (-17%,
//     m06/m119: 32x32 does 4060 FLOP/cyc vs 16x16's 3377).
// Fragment formulas (A k-map, C/D row=(r&3)+8*(r>>2)+4*kh) are HW-verified by the
// round-1 kernel which PASSED the harness refcheck.
__global__ __launch_bounds__(256, 2) void msg_gemm_kernel(
    const float* __restrict__ hv, const _Float16* __restrict__ he16,
    const _Float16* __restrict__ W2rT, const int* __restrict__ ei,
    float* __restrict__ agg, float* __restrict__ xsum) {
    __shared__ _Float16 sB[2][16 * 64 * 8];   // frag f=(nt*8+s): [f*512 + lane*8]
    __shared__ _Float16 sXs[256 * 68];        // [edge][i], padded stride 68
    __shared__ int sDst[256];
    const int t = threadIdx.x;
    const int eb = blockIdx.x * 256;
    const int lane = t & 63;
    const int w = t >> 6;        // wave 0..3: edges [w*64, w*64+64)
    const int l31 = lane & 31;
    const int kh = lane >> 5;    // k-half within each 16-wide K

    if (t < 256) {
        int e = eb + t;
        sDst[t] = (e < EE) ? ei[EE + e] : 0;
    }
    #pragma unroll 4
    for (int rep = 0; rep < 16; rep++) {
        int idx = rep * 256 + t;
        int el = idx >> 4, d4 = idx & 15;
        int e = eb + el;
        float4 v = {0.f, 0.f, 0.f, 0.f};
        if (e < EE) {
            int src = ei[e];
            v = *(const float4*)(hv + (size_t)src * 64 + d4 * 4);
        }
        half4 h4 = {(_Float16)v.x, (_Float16)v.y, (_Float16)v.z, (_Float16)v.w};
        *(half4*)&sXs[el * 68 + d4 * 4] = h4;
    }

    // A fragments: lane holds row l31 (of tile mt), k-elems kh*8..+8 of k-slice s*16.
    half8 heReg[2][8];
    #pragma unroll
    for (int mt = 0; mt < 2; mt++) {
        int row = eb + w * 64 + mt * 32 + l31;
        #pragma unroll
        for (int s = 0; s < 8; s++)
            heReg[mt][s] = *(const half8*)(he16 + (size_t)row * 128 + s * 16 + kh * 8);
    }

    floatx16 Cacc[2][2];
    #pragma unroll
    for (int mt = 0; mt < 2; mt++)
        #pragma unroll
        for (int nt = 0; nt < 2; nt++)
            #pragma unroll
            for (int r = 0; r < 16; r++) Cacc[mt][nt][r] = 0.f;

    // staging: wave w owns frags f = w*4..w*4+3; f = nt*8+s.
    // global elem (o = nt*32+l31, h = s*16+kh*8+e) -> sB[f*512 + lane*8] (conflict-free)
    size_t goff[4]; int woff[4];
    #pragma unroll
    for (int rep = 0; rep < 4; rep++) {
        int f = w * 4 + rep;
        int nt = f >> 3, s = f & 7;
        goff[rep] = (size_t)(nt * 32 + l31) * 8192 + s * 16 + kh * 8;
        woff[rep] = (f * 64 + lane) * 8;
    }
    half8 pre[4];
    {
        #pragma unroll
        for (int rep = 0; rep < 4; rep++) pre[rep] = *(const half8*)(W2rT + goff[rep]);
        #pragma unroll
        for (int rep = 0; rep < 4; rep++) *(half8*)&sB[0][woff[rep]] = pre[rep];
    }
    __syncthreads();

    #pragma unroll 1
    for (int i = 0; i < 64; i++) {
        int buf = i & 1;
        if (i < 63) {
            #pragma unroll
            for (int rep = 0; rep < 4; rep++)
                pre[rep] = *(const half8*)(W2rT + goff[rep] + (size_t)(i + 1) * 128);
        }
        _Float16 xsx[2];
        #pragma unroll
        for (int mt = 0; mt < 2; mt++)
            xsx[mt] = sXs[(w * 64 + mt * 32 + l31) * 68 + i];
        #pragma unroll
        for (int s = 0; s < 8; s++) {
            half8 bfr[2];
            #pragma unroll
            for (int nt = 0; nt < 2; nt++)
                bfr[nt] = *(const half8*)&sB[buf][((nt * 8 + s) * 64 + lane) * 8];
            #pragma unroll
            for (int mt = 0; mt < 2; mt++) {
                half8 afr = heReg[mt][s] * xsx[mt];
                #pragma unroll
                for (int nt = 0; nt < 2; nt++)
                    Cacc[mt][nt] = __builtin_amdgcn_mfma_f32_32x32x16_f16(afr, bfr[nt], Cacc[mt][nt], 0, 0, 0);
            }
        }
        if (i < 63) {
            #pragma unroll
            for (int rep = 0; rep < 4; rep++)
                *(half8*)&sB[buf ^ 1][woff[rep]] = pre[rep];
        }
        __syncthreads();
    }

    // epilogue: 32x32 C/D layout (HW-verified, round-1 passing kernel):
    //   col = l31, row = (r&3) + 8*(r>>2) + 4*kh
    #pragma unroll
    for (int mt = 0; mt < 2; mt++) {
        #pragma unroll
        for (int r = 0; r < 16; r++) {
            int m = (r & 3) + 8 * (r >> 2) + 4 * kh;
            int el = w * 64 + mt * 32 + m;
            if (eb + el < EE) {
                float* ap = agg + (size_t)sDst[el] * 64 + l31;
                atomicAdd(ap, Cacc[mt][0][r]);
                atomicAdd(ap + 32, Cacc[mt][1][r]);
            }
        }
    }
    #pragma unroll 4
    for (int rep = 0; rep < 64; rep++) {
        int idx = rep * 256 + t;
        int el = idx >> 6, d = idx & 63;
        if (eb + el < EE)
            atomicAdd(&xsum[(size_t)sDst[el] * 64 + d], (float)sXs[el * 68 + d]);
    }
}

// ---------------- fused node update: NNConv epilogue + GRU (MFMA) ----------------
// sH LDS round-trip removed: epilogue reads hold directly from hv_in (L2-hot) and
// stores h_new straight to hv_out (rows block-exclusive). LDS 52.2KB -> 3 blocks/CU.
__global__ __launch_bounds__(256, 3) void node_fused_kernel(
    const float* __restrict__ hv_in, float* __restrict__ agg,
    float* __restrict__ xsum, const float* __restrict__ deg,
    const _Float16* __restrict__ W1h, const _Float16* __restrict__ W2h,
    const float* __restrict__ fbias, const float* __restrict__ cb,
    float* __restrict__ hv_out) {
    __shared__ _Float16 sA1[64 * 136];  // [node][k]: k<64 hv, k>=64 xsum/deg
    __shared__ _Float16 sA2[64 * 136];  // [node][k]: k<64 m, k>=64 hv
    __shared__ float sAgg[64 * 68];     // agg/deg fp32
    const int t = threadIdx.x;
    const int nb = blockIdx.x * 64;
    const int n = t >> 2, part = t & 3;
    {
        int gn = nb + n;
        bool valid = gn < NN;
        float inv = 1.f;
        if (valid) inv = 1.f / fmaxf(deg[gn], 1.f);
        #pragma unroll
        for (int c4 = 0; c4 < 4; c4++) {
            int d0 = part * 16 + c4 * 4;
            float4 hvv = {0.f, 0.f, 0.f, 0.f}, agv = {0.f, 0.f, 0.f, 0.f}, xsv = {0.f, 0.f, 0.f, 0.f};
            if (valid) {
                hvv = *(const float4*)(hv_in + (size_t)gn * 64 + d0);
                agv = *(const float4*)(agg + (size_t)gn * 64 + d0);
                xsv = *(const float4*)(xsum + (size_t)gn * 64 + d0);
            }
            agv.x *= inv; agv.y *= inv; agv.z *= inv; agv.w *= inv;
            xsv.x *= inv; xsv.y *= inv; xsv.z *= inv; xsv.w *= inv;
            half4 hvh = {(_Float16)hvv.x, (_Float16)hvv.y, (_Float16)hvv.z, (_Float16)hvv.w};
            half4 xsh = {(_Float16)xsv.x, (_Float16)xsv.y, (_Float16)xsv.z, (_Float16)xsv.w};
            *(half4*)&sA1[n * 136 + d0] = hvh;
            *(half4*)&sA1[n * 136 + 64 + d0] = xsh;
            *(half4*)&sA2[n * 136 + 64 + d0] = hvh;
            *(float4*)&sAgg[n * 68 + d0] = agv;
        }
        // re-zero agg/xsum for the next msg_gemm launch
        if (valid) {
            float4 z = {0.f, 0.f, 0.f, 0.f};
            #pragma unroll
            for (int c4 = 0; c4 < 4; c4++) {
                int d0 = part * 16 + c4 * 4;
                *(float4*)(agg + (size_t)gn * 64 + d0) = z;
                *(float4*)(xsum + (size_t)gn * 64 + d0) = z;
            }
        }
    }
    __syncthreads();

    const int lane = t & 63, w = t >> 6;
    const int col = lane & 15, quad = lane >> 4;

    // ---- stage 1 ----
    floatx4 C1[4];
    #pragma unroll
    for (int nt = 0; nt < 4; nt++) {
        float b = cb[nt * 16 + col];
        C1[nt] = (floatx4){b, b, b, b};
    }
    #pragma unroll
    for (int ks = 0; ks < 4; ks++) {
        half8 a = *(const half8*)&sA1[(w * 16 + col) * 136 + ks * 32 + quad * 8];
        #pragma unroll
        for (int nt = 0; nt < 4; nt++) {
            half8 bfr = *(const half8*)(W1h + (size_t)(nt * 16 + col) * 128 + ks * 32 + quad * 8);
            C1[nt] = __builtin_amdgcn_mfma_f32_16x16x32_f16(a, bfr, C1[nt], 0, 0, 0);
        }
    }
    #pragma unroll
    for (int nt = 0; nt < 4; nt++) {
        #pragma unroll
        for (int r = 0; r < 4; r++) {
            int node = w * 16 + quad * 4 + r;
            int j = nt * 16 + col;
            float m = fmaxf(C1[nt][r] + sAgg[node * 68 + j], 0.f);
            sA2[node * 136 + j] = (_Float16)m;
        }
    }
    __syncthreads();

    // ---- stage 2 ----
    floatx4 C2[16];
    #pragma unroll
    for (int nt2 = 0; nt2 < 16; nt2++) {
        float b = fbias[nt2 * 16 + col];
        C2[nt2] = (floatx4){b, b, b, b};
    }
    #pragma unroll
    for (int ks = 0; ks < 4; ks++) {
        half8 a = *(const half8*)&sA2[(w * 16 + col) * 136 + ks * 32 + quad * 8];
        #pragma unroll
        for (int nt2 = 0; nt2 < 16; nt2++) {
            half8 bfr = *(const half8*)(W2h + (size_t)(nt2 * 16 + col) * 128 + ks * 32 + quad * 8);
            C2[nt2] = __builtin_amdgcn_mfma_f32_16x16x32_f16(a, bfr, C2[nt2], 0, 0, 0);
        }
    }
    // ---- GRU epilogue: direct global hold-read + store (no sH round-trip) ----
    #pragma unroll
    for (int r = 0; r < 4; r++) {
        int node = w * 16 + quad * 4 + r;
        int gn2 = nb + node;
        if (gn2 < NN) {
            #pragma unroll
            for (int jt = 0; jt < 4; jt++) {
                int j = jt * 16 + col;
                float rr = sig_fast(C2[jt][r]);
                float zz = sig_fast(C2[4 + jt][r]);
                float ng = tanh_fast(C2[8 + jt][r] + rr * C2[12 + jt][r]);
                float hold = hv_in[(size_t)gn2 * 64 + j];
                hv_out[(size_t)gn2 * 64 + j] = (1.f - zz) * ng + zz * hold;
            }
        }
    }
}

// ---------------- fused Set2Set (3 steps) + readout, one block per graph ----------------
__global__ __launch_bounds__(256) void set2set_kernel(
    const float* __restrict__ hv,
    const float* __restrict__ lihT, const float* __restrict__ lhhT,
    const float* __restrict__ l_bih, const float* __restrict__ l_bhh,
    const float* __restrict__ lin1T, const float* __restrict__ lin1_b,
    const float* __restrict__ lin2_w, const float* __restrict__ lin2_b,
    float* __restrict__ out) {
    __shared__ float outS[25 * 65];
    __shared__ float qs[128], qh[64], qc[64], gat[256], ew[32], aw[32], red[64];
    int g = blockIdx.x;
    int t = threadIdx.x;
    for (int p = t; p < 25 * 64; p += 256) {
        int j = p >> 6, i = p & 63;
        outS[j * 65 + i] = hv[(size_t)(g * 25 + j) * 64 + i];
    }
    if (t < 128) qs[t] = 0.f;
    if (t < 64) { qh[t] = 0.f; qc[t] = 0.f; }
    __syncthreads();
    for (int it = 0; it < 3; it++) {
        float acc = l_bih[t] + l_bhh[t];
        for (int k = 0; k < 128; k++) acc += qs[k] * lihT[k * 256 + t];
        for (int k = 0; k < 64; k++) acc += qh[k] * lhhT[k * 256 + t];
        gat[t] = acc;
        __syncthreads();
        if (t < 64) {
            float ig = sig_fast(gat[t]);
            float fg = sig_fast(gat[64 + t]);
            float gg = tanh_fast(gat[128 + t]);
            float og = sig_fast(gat[192 + t]);
            float c = fg * qc[t] + ig * gg;
            qc[t] = c;
            qh[t] = og * tanh_fast(c);
        }
        __syncthreads();
        if (t < 25) {
            float e = 0.f;
            for (int i = 0; i < 64; i++) e += outS[t * 65 + i] * qh[i];
            ew[t] = e;
        }
        __syncthreads();
        // wave-parallel softmax over the 25 graph nodes (lanes 0..31 of wave 0)
        if (t < 32) {
            float e = (t < 25) ? ew[t] : -1e30f;
            float mx = e;
            #pragma unroll
            for (int o = 16; o > 0; o >>= 1) mx = fmaxf(mx, __shfl_xor(mx, o, 32));
            float a = (t < 25) ? __expf(e - mx) : 0.f;
            float s = a;
            #pragma unroll
            for (int o = 16; o > 0; o >>= 1) s += __shfl_xor(s, o, 32);
            if (t < 25) aw[t] = a * rcp_fast(s);
        }
        __syncthreads();
        if (t < 64) {
            float r = 0.f;
            for (int j = 0; j < 25; j++) r += aw[j] * outS[j * 65 + t];
            qs[t] = qh[t];
            qs[64 + t] = r;
        }
        __syncthreads();
    }
    if (t < 64) {
        float y1 = lin1_b[t];
        for (int k = 0; k < 128; k++) y1 += qs[k] * lin1T[k * 64 + t];
        y1 = fmaxf(y1, 0.f);
        red[t] = y1 * lin2_w[t];
    }
    __syncthreads();
    if (t == 0) {
        float y = lin2_b[0];
        for (int i = 0; i < 64; i++) y += red[i];
        out[g] = y;
    }
}

extern "C" void kernel_launch(void* const* d_in, const int* in_sizes, int n_in,
                              void* d_out, int out_size, void* d_ws, size_t ws_size,
                              hipStream_t stream) {
    const float* x        = (const float*)d_in[0];
    const float* ea       = (const float*)d_in[1];
    const int*   ei       = (const int*)  d_in[2];
    const float* lin0_w   = (const float*)d_in[4];
    const float* lin0_b   = (const float*)d_in[5];
    const float* mlp_w1   = (const float*)d_in[6];
    const float* mlp_b1   = (const float*)d_in[7];
    const float* mlp_w2   = (const float*)d_in[8];
    const float* mlp_b2   = (const float*)d_in[9];
    const float* root     = (const float*)d_in[10];
    const float* conv_b   = (const float*)d_in[11];
    const float* gru_wih  = (const float*)d_in[12];
    const float* gru_whh  = (const float*)d_in[13];
    const float* gru_bih  = (const float*)d_in[14];
    const float* gru_bhh  = (const float*)d_in[15];
    const float* lstm_wih = (const float*)d_in[16];
    const float* lstm_whh = (const float*)d_in[17];
    const float* lstm_bih = (const float*)d_in[18];
    const float* lstm_bhh = (const float*)d_in[19];
    const float* lin1_w   = (const float*)d_in[20];
    const float* lin1_b   = (const float*)d_in[21];
    const float* lin2_w   = (const float*)d_in[22];
    const float* lin2_b   = (const float*)d_in[23];
    float* out = (float*)d_out;

    // ---- workspace carve ----
    char* base = (char*)d_ws;
    size_t off = 0;
    auto carve = [&](size_t bytes) -> void* {
        void* r = base + off;
        off = (off + bytes + 255) & ~(size_t)255;
        return r;
    };
    float* hv   = (float*)carve((size_t)NN * 64 * 4);
    float* agg  = (float*)carve((size_t)NN * 64 * 4);   // agg+xsum+deg adjacent: one memset
    float* xsum = (float*)carve((size_t)NN * 64 * 4);
    float* deg  = (float*)carve((size_t)NN * 4);
    float* lihT = (float*)carve(128 * 256 * 4);
    float* lhhT = (float*)carve(64 * 256 * 4);
    float* l1T  = (float*)carve(128 * 64 * 4);
    float* fbias = (float*)carve(256 * 4);
    _Float16* he16 = (_Float16*)carve((size_t)EPAD2 * 128 * 2);
    _Float16* W2rT = (_Float16*)carve((size_t)64 * 8192 * 2);
    _Float16* W1h  = (_Float16*)carve((size_t)64 * 128 * 2);
    _Float16* W2h  = (_Float16*)carve((size_t)256 * 128 * 2);

    // ---- preamble: one memset (agg+xsum+deg contiguous) + one fused prep kernel ----
    hipMemsetAsync(agg, 0, (size_t)NN * 64 * 4 * 2 + (size_t)NN * 4, stream);
    prep_fused_kernel<<<EPAD2 * 16 / 256, 256, 0, stream>>>(
        x, lin0_w, lin0_b, hv,
        ea, mlp_w1, mlp_b1, he16, ei, deg,
        mlp_w2, W2rT,
        lstm_wih, lstm_whh, lin1_w, lihT, lhhT, l1T,
        root, mlp_b2, gru_wih, gru_whh, gru_bih, gru_bhh,
        W1h, W2h, fbias);

    // ---- 3 message-passing + GRU iterations (node_fused re-zeros agg/xsum) ----
    for (int it = 0; it < 3; it++) {
        msg_gemm_kernel<<<EPAD / 256, 256, 0, stream>>>(hv, he16, W2rT, ei, agg, xsum);
        node_fused_kernel<<<(NN + 63) / 64, 256, 0, stream>>>(hv, agg, xsum, deg,
                                                              W1h, W2h, fbias, conv_b, hv);
    }

    // ---- Set2Set + readout ----
    set2set_kernel<<<BB, 256, 0, stream>>>(hv, lihT, lhhT, lstm_bih, lstm_bhh,
                                           l1T, lin1_b, lin2_w, lin2_b, out);
}